// Round 3
// baseline (804.733 us; speedup 1.0000x reference)
//
#include <hip/hip_runtime.h>
#include <stdint.h>

#define DIM 128

typedef __attribute__((ext_vector_type(8))) short short8;
typedef __attribute__((ext_vector_type(4))) float floatx4;

__device__ __forceinline__ unsigned short f2bf(float f){
  union { float f; unsigned int i; } c; c.f = f;
  unsigned int u = c.i;
  return (unsigned short)((u + 0x7fffu + ((u >> 16) & 1u)) >> 16);
}

// ---- CSR build -------------------------------------------------------------

__global__ __launch_bounds__(256) void k_hist(const int* __restrict__ dst, int E,
                                              int* __restrict__ deg){
  int e = blockIdx.x * 256 + threadIdx.x;
  if (e < E) atomicAdd(&deg[dst[e]], 1);
}

// per-block exclusive scan over 1024 elements
__global__ __launch_bounds__(256) void k_scan1(const int* __restrict__ deg, int N,
    int* __restrict__ out, int* __restrict__ bsum){
  __shared__ int sd[256];
  int t = threadIdx.x;
  int base = blockIdx.x * 1024 + t * 4;
  int v0=0, v1=0, v2=0, v3=0;
  if (base + 3 < N) { int4 q = *(const int4*)(deg + base); v0=q.x; v1=q.y; v2=q.z; v3=q.w; }
  else {
    if (base + 0 < N) v0 = deg[base + 0];
    if (base + 1 < N) v1 = deg[base + 1];
    if (base + 2 < N) v2 = deg[base + 2];
  }
  int s = v0 + v1 + v2 + v3;
  sd[t] = s;
  __syncthreads();
  #pragma unroll
  for (int off = 1; off < 256; off <<= 1){
    int x = (t >= off) ? sd[t - off] : 0;
    __syncthreads();
    sd[t] += x;
    __syncthreads();
  }
  int inc = sd[t];
  int exc = inc - s;
  if (base + 0 < N) out[base + 0] = exc;
  if (base + 1 < N) out[base + 1] = exc + v0;
  if (base + 2 < N) out[base + 2] = exc + v0 + v1;
  if (base + 3 < N) out[base + 3] = exc + v0 + v1 + v2;
  if (t == 255) bsum[blockIdx.x] = inc;
}

__global__ __launch_bounds__(128) void k_scan2(int* __restrict__ bsum, int nb){
  __shared__ int sd[128];
  int t = threadIdx.x;
  int v = (t < nb) ? bsum[t] : 0;
  sd[t] = v;
  __syncthreads();
  #pragma unroll
  for (int off = 1; off < 128; off <<= 1){
    int x = (t >= off) ? sd[t - off] : 0;
    __syncthreads();
    sd[t] += x;
    __syncthreads();
  }
  if (t < nb) bsum[t] = sd[t] - v;  // exclusive block offsets
}

__global__ __launch_bounds__(256) void k_scan3(int* __restrict__ rowptr,
    const int* __restrict__ bsum, int N, int E, int* __restrict__ cursor){
  int i = blockIdx.x * 256 + threadIdx.x;
  if (i < N){
    int v = rowptr[i] + bsum[i >> 10];
    rowptr[i] = v;
    cursor[i] = v;
  }
  if (i == 0) rowptr[N] = E;
}

__global__ __launch_bounds__(256) void k_fill(const int* __restrict__ src,
    const int* __restrict__ dst, int E, int* __restrict__ cursor, int* __restrict__ col){
  int e = blockIdx.x * 256 + threadIdx.x;
  if (e < E){
    int d = dst[e];
    int pos = atomicAdd(&cursor[d], 1);
    col[pos] = src[e];
  }
}

// ---- mean aggregation: one wave per node, f32 in, f32 accumulate, bf16 out -

__global__ __launch_bounds__(256) void k_agg(const float* __restrict__ feat,
    const int* __restrict__ rowptr, const int* __restrict__ col,
    unsigned short* __restrict__ out, int N){
  int wid = (blockIdx.x * 256 + threadIdx.x) >> 6;
  if (wid >= N) return;
  int lane = threadIdx.x & 63;
  int beg = rowptr[wid], end = rowptr[wid + 1];
  float a0 = 0.f, a1 = 0.f;
  int off = lane * 2;
  for (int e = beg; e < end; ++e){
    int s = col[e];
    float2 v = *(const float2*)(feat + (size_t)s * DIM + off);
    a0 += v.x;
    a1 += v.y;
  }
  int d = end - beg;
  float r = 1.0f / (float)(d > 1 ? d : 1);
  a0 *= r; a1 *= r;
  unsigned int o = (unsigned int)f2bf(a0) | ((unsigned int)f2bf(a1) << 16);
  *(unsigned int*)(out + (size_t)wid * DIM + off) = o;
}

// ---- fused dual GEMM: out = relu(A1@Wl + A2@Wr + bias), M x 128, K=128+128 -
// A1 bf16 (aggregated), A2 f32 (root features, converted in-register),
// W f32 -> bf16 during swizzled LDS staging, bias f32, out f32.
// In-place safe with out == A2: each 16-row task reads only its own rows
// before storing them, and each row is owned by exactly one task.

__global__ __launch_bounds__(256) void k_gemm(const unsigned short* __restrict__ A1,
    const float* __restrict__ A2,
    const float* __restrict__ Wl, const float* __restrict__ Wr,
    const float* __restrict__ bias,
    float* __restrict__ out, int M)
{
  __shared__ unsigned short lds[2 * 128 * 128];  // 64 KiB (bf16 WlT | WrT)
  for (int h = threadIdx.x; h < 128 * 128; h += 256){
    int k = h >> 7, n = h & 127;               // W[k][n]
    int idx = n * 128 + ((((k >> 3) ^ (n & 7)) << 3)) + (k & 7);
    lds[idx]         = f2bf(Wl[h]);
    lds[16384 + idx] = f2bf(Wr[h]);
  }
  __syncthreads();
  int lane = threadIdx.x & 63;
  int c = lane & 15, quad = lane >> 4;
  int gwid = blockIdx.x * 4 + (threadIdx.x >> 6);
  int nwaves = gridDim.x * 4;
  int ntasks = M >> 4;  // M % 16 == 0 (100000/16 = 6250)
  for (int task = gwid; task < ntasks; task += nwaves){
    int row0 = task << 4;
    floatx4 acc[8];
    #pragma unroll
    for (int j = 0; j < 8; ++j) acc[j] = (floatx4){0.f, 0.f, 0.f, 0.f};
    const unsigned short* ap1 = A1 + (size_t)(row0 + c) * DIM + quad * 8;
    const float*          ap2 = A2 + (size_t)(row0 + c) * DIM + quad * 8;
    // half 1: A1 (bf16) @ Wl
    #pragma unroll
    for (int km = 0; km < 4; ++km){
      short8 a = *(const short8*)(ap1 + km * 32);
      int kb = (km << 2) + quad;
      #pragma unroll
      for (int j = 0; j < 8; ++j){
        short8 b = *(const short8*)(&lds[(j * 16 + c) * 128 + ((kb ^ (c & 7)) << 3)]);
        acc[j] = __builtin_amdgcn_mfma_f32_16x16x32_bf16(a, b, acc[j], 0, 0, 0);
      }
    }
    // half 2: A2 (f32 -> bf16) @ Wr
    #pragma unroll
    for (int km = 0; km < 4; ++km){
      float4 p0 = *(const float4*)(ap2 + km * 32);
      float4 p1 = *(const float4*)(ap2 + km * 32 + 4);
      union { short8 v; unsigned short u[8]; } ua;
      ua.u[0] = f2bf(p0.x); ua.u[1] = f2bf(p0.y);
      ua.u[2] = f2bf(p0.z); ua.u[3] = f2bf(p0.w);
      ua.u[4] = f2bf(p1.x); ua.u[5] = f2bf(p1.y);
      ua.u[6] = f2bf(p1.z); ua.u[7] = f2bf(p1.w);
      int kb = (km << 2) + quad;
      #pragma unroll
      for (int j = 0; j < 8; ++j){
        short8 b = *(const short8*)(&lds[16384 + (j * 16 + c) * 128 + ((kb ^ (c & 7)) << 3)]);
        acc[j] = __builtin_amdgcn_mfma_f32_16x16x32_bf16(ua.v, b, acc[j], 0, 0, 0);
      }
    }
    #pragma unroll
    for (int j = 0; j < 8; ++j){
      int colIdx = j * 16 + c;
      float bv = bias[colIdx];
      #pragma unroll
      for (int r = 0; r < 4; ++r){
        int row = row0 + quad * 4 + r;
        float v = acc[j][r] + bv;
        out[(size_t)row * DIM + colIdx] = fmaxf(v, 0.f);
      }
    }
  }
}

// ---- host ------------------------------------------------------------------
// ws: rowptr 400KB + deg/cursor 400KB + bsum 1KB + col 6.4MB + aggb 25.6MB
//     ~= 32.9 MB. h1 (f32) lives in d_out; layer-2 gemm runs in-place.

extern "C" void kernel_launch(void* const* d_in, const int* in_sizes, int n_in,
                              void* d_out, int out_size, void* d_ws, size_t ws_size,
                              hipStream_t stream)
{
  const float* x   = (const float*)d_in[0];  // f32 [N][128]
  const int*   ei  = (const int*)d_in[1];    // int32 [2][E]
  const float* Wl1 = (const float*)d_in[2];
  const float* bl1 = (const float*)d_in[3];
  const float* Wr1 = (const float*)d_in[4];
  const float* Wl2 = (const float*)d_in[5];
  const float* bl2 = (const float*)d_in[6];
  const float* Wr2 = (const float*)d_in[7];

  const int N = in_sizes[0] / DIM;
  const int E = in_sizes[1] / 2;
  const int* src  = ei;
  const int* dstI = ei + E;

  char* p = (char*)d_ws;
  auto alloc = [&](size_t bytes) -> char* {
    char* r = p; p += (bytes + 255) & ~((size_t)255); return r;
  };
  int* rowptr = (int*)alloc((size_t)(N + 1) * 4);
  int* deg    = (int*)alloc((size_t)N * 4);      // reused as cursor after scan
  int* bsum   = (int*)alloc(1024);
  int* col    = (int*)alloc((size_t)E * 4);
  unsigned short* aggb = (unsigned short*)alloc((size_t)N * DIM * 2);
  float* h1 = (float*)d_out;                     // layer-1 output lives in d_out

  hipMemsetAsync(deg, 0, (size_t)N * 4, stream);

  int gE = (E + 255) / 256;
  k_hist<<<gE, 256, 0, stream>>>(dstI, E, deg);

  int nb = (N + 1023) / 1024;  // 98 for N=100000, fits in k_scan2's 128
  k_scan1<<<nb, 256, 0, stream>>>(deg, N, rowptr, bsum);
  k_scan2<<<1, 128, 0, stream>>>(bsum, nb);
  k_scan3<<<(N + 255) / 256, 256, 0, stream>>>(rowptr, bsum, N, E, /*cursor=*/deg);
  k_fill<<<gE, 256, 0, stream>>>(src, dstI, E, /*cursor=*/deg, col);

  int gAgg = (N * 64 + 255) / 256;  // one wave per node
  // layer 1: agg(x) -> aggb ; h1 = relu(aggb@Wl1 + x@Wr1 + b1) -> d_out (f32)
  k_agg<<<gAgg, 256, 0, stream>>>(x, rowptr, col, aggb, N);
  k_gemm<<<1024, 256, 0, stream>>>(aggb, x, Wl1, Wr1, bl1, h1, N);
  // layer 2: agg(h1) -> aggb ; out = relu(aggb@Wl2 + h1@Wr2 + b2) -> d_out (in-place)
  k_agg<<<gAgg, 256, 0, stream>>>(h1, rowptr, col, aggb, N);
  k_gemm<<<1024, 256, 0, stream>>>(aggb, h1, Wl2, Wr2, bl2, (float*)d_out, N);
}

// Round 4
// 566.314 us; speedup vs baseline: 1.4210x; 1.4210x over previous
//
#include <hip/hip_runtime.h>
#include <stdint.h>

#define DIM 128

typedef __attribute__((ext_vector_type(8))) short short8;
typedef __attribute__((ext_vector_type(4))) float floatx4;

__device__ __forceinline__ unsigned short f2bf(float f){
  union { float f; unsigned int i; } c; c.f = f;
  unsigned int u = c.i;
  return (unsigned short)((u + 0x7fffu + ((u >> 16) & 1u)) >> 16);
}
__device__ __forceinline__ float up_lo(unsigned int v){ return __uint_as_float(v << 16); }
__device__ __forceinline__ float up_hi(unsigned int v){ return __uint_as_float(v & 0xffff0000u); }

// ---- f32 -> bf16 cast (vectorized, grid-stride) ----------------------------

__global__ __launch_bounds__(256) void k_cast(const float* __restrict__ in,
    unsigned short* __restrict__ out, int n4){
  int i = blockIdx.x * 256 + threadIdx.x;
  int stride = gridDim.x * 256;
  for (; i < n4; i += stride){
    float4 v = ((const float4*)in)[i];
    ushort4 o;
    o.x = f2bf(v.x); o.y = f2bf(v.y); o.z = f2bf(v.z); o.w = f2bf(v.w);
    ((ushort4*)out)[i] = o;
  }
}

// ---- CSR build -------------------------------------------------------------

__global__ __launch_bounds__(256) void k_hist(const int* __restrict__ dst, int E,
                                              int* __restrict__ deg){
  int e = blockIdx.x * 256 + threadIdx.x;
  if (e < E) atomicAdd(&deg[dst[e]], 1);
}

__global__ __launch_bounds__(256) void k_scan1(const int* __restrict__ deg, int N,
    int* __restrict__ out, int* __restrict__ bsum){
  __shared__ int sd[256];
  int t = threadIdx.x;
  int base = blockIdx.x * 1024 + t * 4;
  int v0=0, v1=0, v2=0, v3=0;
  if (base + 3 < N) { int4 q = *(const int4*)(deg + base); v0=q.x; v1=q.y; v2=q.z; v3=q.w; }
  else {
    if (base + 0 < N) v0 = deg[base + 0];
    if (base + 1 < N) v1 = deg[base + 1];
    if (base + 2 < N) v2 = deg[base + 2];
  }
  int s = v0 + v1 + v2 + v3;
  sd[t] = s;
  __syncthreads();
  #pragma unroll
  for (int off = 1; off < 256; off <<= 1){
    int x = (t >= off) ? sd[t - off] : 0;
    __syncthreads();
    sd[t] += x;
    __syncthreads();
  }
  int inc = sd[t];
  int exc = inc - s;
  if (base + 0 < N) out[base + 0] = exc;
  if (base + 1 < N) out[base + 1] = exc + v0;
  if (base + 2 < N) out[base + 2] = exc + v0 + v1;
  if (base + 3 < N) out[base + 3] = exc + v0 + v1 + v2;
  if (t == 255) bsum[blockIdx.x] = inc;
}

__global__ __launch_bounds__(128) void k_scan2(int* __restrict__ bsum, int nb){
  __shared__ int sd[128];
  int t = threadIdx.x;
  int v = (t < nb) ? bsum[t] : 0;
  sd[t] = v;
  __syncthreads();
  #pragma unroll
  for (int off = 1; off < 128; off <<= 1){
    int x = (t >= off) ? sd[t - off] : 0;
    __syncthreads();
    sd[t] += x;
    __syncthreads();
  }
  if (t < nb) bsum[t] = sd[t] - v;
}

__global__ __launch_bounds__(256) void k_scan3(int* __restrict__ rowptr,
    const int* __restrict__ bsum, int N, int E, int* __restrict__ cursor){
  int i = blockIdx.x * 256 + threadIdx.x;
  if (i < N){
    int v = rowptr[i] + bsum[i >> 10];
    rowptr[i] = v;
    cursor[i] = v;
  }
  if (i == 0) rowptr[N] = E;
}

__global__ __launch_bounds__(256) void k_fill(const int* __restrict__ src,
    const int* __restrict__ dst, int E, int* __restrict__ cursor, int* __restrict__ col){
  int e = blockIdx.x * 256 + threadIdx.x;
  if (e < E){
    int d = dst[e];
    int pos = atomicAdd(&cursor[d], 1);
    col[pos] = src[e];
  }
}

// ---- mean aggregation: one wave/node, unroll x4 for MLP, bf16 out ----------

template<bool BF>
__global__ __launch_bounds__(256) void k_agg(const void* __restrict__ feat_,
    const int* __restrict__ rowptr, const int* __restrict__ col,
    unsigned short* __restrict__ out, int N){
  int wid = (blockIdx.x * 256 + threadIdx.x) >> 6;
  if (wid >= N) return;
  int lane = threadIdx.x & 63;
  int beg = rowptr[wid], end = rowptr[wid + 1];
  float a0 = 0.f, a1 = 0.f;
  int off = lane * 2;
  int e = beg;
  if (BF){
    const unsigned short* feat = (const unsigned short*)feat_;
    for (; e + 4 <= end; e += 4){
      int s0 = col[e], s1 = col[e+1], s2 = col[e+2], s3 = col[e+3];
      unsigned int v0 = *(const unsigned int*)(feat + (size_t)s0 * DIM + off);
      unsigned int v1 = *(const unsigned int*)(feat + (size_t)s1 * DIM + off);
      unsigned int v2 = *(const unsigned int*)(feat + (size_t)s2 * DIM + off);
      unsigned int v3 = *(const unsigned int*)(feat + (size_t)s3 * DIM + off);
      a0 += up_lo(v0) + up_lo(v1) + up_lo(v2) + up_lo(v3);
      a1 += up_hi(v0) + up_hi(v1) + up_hi(v2) + up_hi(v3);
    }
    for (; e < end; ++e){
      unsigned int v = *(const unsigned int*)(feat + (size_t)col[e] * DIM + off);
      a0 += up_lo(v); a1 += up_hi(v);
    }
  } else {
    const float* feat = (const float*)feat_;
    for (; e + 4 <= end; e += 4){
      int s0 = col[e], s1 = col[e+1], s2 = col[e+2], s3 = col[e+3];
      float2 v0 = *(const float2*)(feat + (size_t)s0 * DIM + off);
      float2 v1 = *(const float2*)(feat + (size_t)s1 * DIM + off);
      float2 v2 = *(const float2*)(feat + (size_t)s2 * DIM + off);
      float2 v3 = *(const float2*)(feat + (size_t)s3 * DIM + off);
      a0 += v0.x + v1.x + v2.x + v3.x;
      a1 += v0.y + v1.y + v2.y + v3.y;
    }
    for (; e < end; ++e){
      float2 v = *(const float2*)(feat + (size_t)col[e] * DIM + off);
      a0 += v.x; a1 += v.y;
    }
  }
  int d = end - beg;
  float r = 1.0f / (float)(d > 1 ? d : 1);
  a0 *= r; a1 *= r;
  unsigned int o = (unsigned int)f2bf(a0) | ((unsigned int)f2bf(a1) << 16);
  *(unsigned int*)(out + (size_t)wid * DIM + off) = o;
}

// ---- fused dual GEMM: out = relu(A1@Wl + A2@Wr + bias) ---------------------
// A1 bf16; A2 f32 or bf16 (template); out f32 or bf16 (template).
// W f32 -> bf16 during swizzled LDS staging. In-place safe when out aliases
// A1/A2 with SAME row geometry: rows are task-private, reads precede stores.

template<bool A2BF, bool OUTBF>
__global__ __launch_bounds__(256) void k_gemm(const unsigned short* __restrict__ A1,
    const float* __restrict__ A2f, const unsigned short* __restrict__ A2b,
    const float* __restrict__ Wl, const float* __restrict__ Wr,
    const float* __restrict__ bias,
    float* __restrict__ outf, unsigned short* __restrict__ outb, int M)
{
  __shared__ unsigned short lds[2 * 128 * 128];  // 64 KiB (bf16 WlT | WrT)
  for (int h = threadIdx.x; h < 128 * 128; h += 256){
    int k = h >> 7, n = h & 127;               // W[k][n]
    int idx = n * 128 + ((((k >> 3) ^ (n & 7)) << 3)) + (k & 7);
    lds[idx]         = f2bf(Wl[h]);
    lds[16384 + idx] = f2bf(Wr[h]);
  }
  __syncthreads();
  int lane = threadIdx.x & 63;
  int c = lane & 15, quad = lane >> 4;
  int gwid = blockIdx.x * 4 + (threadIdx.x >> 6);
  int nwaves = gridDim.x * 4;
  int ntasks = M >> 4;
  for (int task = gwid; task < ntasks; task += nwaves){
    int row0 = task << 4;
    floatx4 acc[8];
    #pragma unroll
    for (int j = 0; j < 8; ++j) acc[j] = (floatx4){0.f, 0.f, 0.f, 0.f};
    const unsigned short* ap1 = A1 + (size_t)(row0 + c) * DIM + quad * 8;
    // half 1: A1 (bf16) @ Wl
    #pragma unroll
    for (int km = 0; km < 4; ++km){
      short8 a = *(const short8*)(ap1 + km * 32);
      int kb = (km << 2) + quad;
      #pragma unroll
      for (int j = 0; j < 8; ++j){
        short8 b = *(const short8*)(&lds[(j * 16 + c) * 128 + ((kb ^ (c & 7)) << 3)]);
        acc[j] = __builtin_amdgcn_mfma_f32_16x16x32_bf16(a, b, acc[j], 0, 0, 0);
      }
    }
    // half 2: A2 @ Wr
    #pragma unroll
    for (int km = 0; km < 4; ++km){
      short8 av;
      if (A2BF){
        av = *(const short8*)(A2b + (size_t)(row0 + c) * DIM + quad * 8 + km * 32);
      } else {
        const float* ap2 = A2f + (size_t)(row0 + c) * DIM + quad * 8;
        float4 p0 = *(const float4*)(ap2 + km * 32);
        float4 p1 = *(const float4*)(ap2 + km * 32 + 4);
        union { short8 v; unsigned short u[8]; } ua;
        ua.u[0] = f2bf(p0.x); ua.u[1] = f2bf(p0.y);
        ua.u[2] = f2bf(p0.z); ua.u[3] = f2bf(p0.w);
        ua.u[4] = f2bf(p1.x); ua.u[5] = f2bf(p1.y);
        ua.u[6] = f2bf(p1.z); ua.u[7] = f2bf(p1.w);
        av = ua.v;
      }
      int kb = (km << 2) + quad;
      #pragma unroll
      for (int j = 0; j < 8; ++j){
        short8 b = *(const short8*)(&lds[16384 + (j * 16 + c) * 128 + ((kb ^ (c & 7)) << 3)]);
        acc[j] = __builtin_amdgcn_mfma_f32_16x16x32_bf16(av, b, acc[j], 0, 0, 0);
      }
    }
    #pragma unroll
    for (int j = 0; j < 8; ++j){
      int colIdx = j * 16 + c;
      float bv = bias[colIdx];
      #pragma unroll
      for (int r = 0; r < 4; ++r){
        int row = row0 + quad * 4 + r;
        float v = fmaxf(acc[j][r] + bv, 0.f);
        if (OUTBF) outb[(size_t)row * DIM + colIdx] = f2bf(v);
        else       outf[(size_t)row * DIM + colIdx] = v;
      }
    }
  }
}

// ---- host ------------------------------------------------------------------

extern "C" void kernel_launch(void* const* d_in, const int* in_sizes, int n_in,
                              void* d_out, int out_size, void* d_ws, size_t ws_size,
                              hipStream_t stream)
{
  const float* x   = (const float*)d_in[0];
  const int*   ei  = (const int*)d_in[1];
  const float* Wl1 = (const float*)d_in[2];
  const float* bl1 = (const float*)d_in[3];
  const float* Wr1 = (const float*)d_in[4];
  const float* Wl2 = (const float*)d_in[5];
  const float* bl2 = (const float*)d_in[6];
  const float* Wr2 = (const float*)d_in[7];

  const int N = in_sizes[0] / DIM;
  const int E = in_sizes[1] / 2;
  const int* src  = ei;
  const int* dstI = ei + E;

  char* p = (char*)d_ws;
  auto alloc = [&](size_t bytes) -> char* {
    char* r = p; p += (bytes + 255) & ~((size_t)255); return r;
  };
  int* rowptr = (int*)alloc((size_t)(N + 1) * 4);
  int* deg    = (int*)alloc((size_t)N * 4);      // reused as cursor after scan
  int* bsum   = (int*)alloc(1024);
  int* col    = (int*)alloc((size_t)E * 4);
  unsigned short* aggb = (unsigned short*)alloc((size_t)N * DIM * 2);
  size_t need_small = (size_t)(p - (char*)d_ws);
  unsigned short* xb  = (unsigned short*)alloc((size_t)N * DIM * 2);
  unsigned short* h1b = (unsigned short*)alloc((size_t)N * DIM * 2);
  size_t need_big = (size_t)(p - (char*)d_ws);
  const bool big = (ws_size >= need_big);
  (void)need_small;

  hipMemsetAsync(deg, 0, (size_t)N * 4, stream);

  int gE = (E + 255) / 256;
  k_hist<<<gE, 256, 0, stream>>>(dstI, E, deg);
  int nb = (N + 1023) / 1024;
  k_scan1<<<nb, 256, 0, stream>>>(deg, N, rowptr, bsum);
  k_scan2<<<1, 128, 0, stream>>>(bsum, nb);
  k_scan3<<<(N + 255) / 256, 256, 0, stream>>>(rowptr, bsum, N, E, /*cursor=*/deg);
  k_fill<<<gE, 256, 0, stream>>>(src, dstI, E, /*cursor=*/deg, col);

  int gAgg = (N * 64 + 255) / 256;  // one wave per node

  if (big){
    // all-bf16 path: xb = bf16(x); h1 exists only as bf16
    int n4 = N * DIM / 4;
    k_cast<<<8192, 256, 0, stream>>>(x, xb, n4);
    k_agg<true><<<gAgg, 256, 0, stream>>>(xb, rowptr, col, aggb, N);
    k_gemm<true, true><<<512, 256, 0, stream>>>(aggb, nullptr, xb, Wl1, Wr1, bl1,
                                                nullptr, h1b, N);
    k_agg<true><<<gAgg, 256, 0, stream>>>(h1b, rowptr, col, aggb, N);
    k_gemm<true, false><<<512, 256, 0, stream>>>(aggb, nullptr, h1b, Wl2, Wr2, bl2,
                                                 (float*)d_out, nullptr, N);
  } else {
    // proven 33 MB footprint: f32 gathers, f32 h1 in d_out, in-place gemm2
    float* h1 = (float*)d_out;
    k_agg<false><<<gAgg, 256, 0, stream>>>(x, rowptr, col, aggb, N);
    k_gemm<false, false><<<512, 256, 0, stream>>>(aggb, x, nullptr, Wl1, Wr1, bl1,
                                                  h1, nullptr, N);
    k_agg<false><<<gAgg, 256, 0, stream>>>(h1, rowptr, col, aggb, N);
    k_gemm<false, false><<<512, 256, 0, stream>>>(aggb, h1, nullptr, Wl2, Wr2, bl2,
                                                  (float*)d_out, nullptr, N);
  }
}

// Round 5
// 535.810 us; speedup vs baseline: 1.5019x; 1.0569x over previous
//
#include <hip/hip_runtime.h>
#include <stdint.h>

#define DIM 128

typedef __attribute__((ext_vector_type(8))) short short8;
typedef __attribute__((ext_vector_type(4))) float floatx4;

__device__ __forceinline__ unsigned short f2bf(float f){
  union { float f; unsigned int i; } c; c.f = f;
  unsigned int u = c.i;
  return (unsigned short)((u + 0x7fffu + ((u >> 16) & 1u)) >> 16);
}
__device__ __forceinline__ float up_lo(unsigned int v){ return __uint_as_float(v << 16); }
__device__ __forceinline__ float up_hi(unsigned int v){ return __uint_as_float(v & 0xffff0000u); }

// ---- f32 -> bf16 cast (vectorized, grid-stride) ----------------------------

__global__ __launch_bounds__(256) void k_cast(const float* __restrict__ in,
    unsigned short* __restrict__ out, int n4){
  int i = blockIdx.x * 256 + threadIdx.x;
  int stride = gridDim.x * 256;
  for (; i < n4; i += stride){
    float4 v = ((const float4*)in)[i];
    ushort4 o;
    o.x = f2bf(v.x); o.y = f2bf(v.y); o.z = f2bf(v.z); o.w = f2bf(v.w);
    ((ushort4*)out)[i] = o;
  }
}

// ---- CSR build -------------------------------------------------------------

__global__ __launch_bounds__(256) void k_hist(const int* __restrict__ dst, int E,
                                              int* __restrict__ deg){
  int e = blockIdx.x * 256 + threadIdx.x;
  if (e < E) atomicAdd(&deg[dst[e]], 1);
}

__global__ __launch_bounds__(256) void k_scan1(const int* __restrict__ deg, int N,
    int* __restrict__ out, int* __restrict__ bsum){
  __shared__ int sd[256];
  int t = threadIdx.x;
  int base = blockIdx.x * 1024 + t * 4;
  int v0=0, v1=0, v2=0, v3=0;
  if (base + 3 < N) { int4 q = *(const int4*)(deg + base); v0=q.x; v1=q.y; v2=q.z; v3=q.w; }
  else {
    if (base + 0 < N) v0 = deg[base + 0];
    if (base + 1 < N) v1 = deg[base + 1];
    if (base + 2 < N) v2 = deg[base + 2];
  }
  int s = v0 + v1 + v2 + v3;
  sd[t] = s;
  __syncthreads();
  #pragma unroll
  for (int off = 1; off < 256; off <<= 1){
    int x = (t >= off) ? sd[t - off] : 0;
    __syncthreads();
    sd[t] += x;
    __syncthreads();
  }
  int inc = sd[t];
  int exc = inc - s;
  if (base + 0 < N) out[base + 0] = exc;
  if (base + 1 < N) out[base + 1] = exc + v0;
  if (base + 2 < N) out[base + 2] = exc + v0 + v1;
  if (base + 3 < N) out[base + 3] = exc + v0 + v1 + v2;
  if (t == 255) bsum[blockIdx.x] = inc;
}

__global__ __launch_bounds__(128) void k_scan2(int* __restrict__ bsum, int nb){
  __shared__ int sd[128];
  int t = threadIdx.x;
  int v = (t < nb) ? bsum[t] : 0;
  sd[t] = v;
  __syncthreads();
  #pragma unroll
  for (int off = 1; off < 128; off <<= 1){
    int x = (t >= off) ? sd[t - off] : 0;
    __syncthreads();
    sd[t] += x;
    __syncthreads();
  }
  if (t < nb) bsum[t] = sd[t] - v;
}

__global__ __launch_bounds__(256) void k_scan3(int* __restrict__ rowptr,
    const int* __restrict__ bsum, int N, int E, int* __restrict__ cursor){
  int i = blockIdx.x * 256 + threadIdx.x;
  if (i < N){
    int v = rowptr[i] + bsum[i >> 10];
    rowptr[i] = v;
    cursor[i] = v;
  }
  if (i == 0) rowptr[N] = E;
}

__global__ __launch_bounds__(256) void k_fill(const int* __restrict__ src,
    const int* __restrict__ dst, int E, int* __restrict__ cursor, int* __restrict__ col){
  int e = blockIdx.x * 256 + threadIdx.x;
  if (e < E){
    int d = dst[e];
    int pos = atomicAdd(&cursor[d], 1);
    col[pos] = src[e];
  }
}

// ---- bf16 mean aggregation: quarter-wave row gathers, 16 edges in flight ---
// One wave per node. Each 16-lane quarter reads one full 256B row per VMEM
// instruction (lane s reads uint4 = 8 bf16 dims at s*16B). 4 quarters = 4
// edges per instruction; unroll x4 = 16 edges in flight. Cross-quarter
// reduce via shfl_xor(16/32) at the end.

__device__ __forceinline__ void acc8(float* a, uint4 u){
  a[0] += up_lo(u.x); a[1] += up_hi(u.x);
  a[2] += up_lo(u.y); a[3] += up_hi(u.y);
  a[4] += up_lo(u.z); a[5] += up_hi(u.z);
  a[6] += up_lo(u.w); a[7] += up_hi(u.w);
}

__global__ __launch_bounds__(256) void k_agg_bf(const unsigned short* __restrict__ feat,
    const int* __restrict__ rowptr, const int* __restrict__ col,
    unsigned short* __restrict__ out, int N){
  int wid = (blockIdx.x * 256 + threadIdx.x) >> 6;
  if (wid >= N) return;
  int lane = threadIdx.x & 63;
  int q = lane >> 4, s = lane & 15;
  int beg = rowptr[wid], end = rowptr[wid + 1];
  float a[8];
  #pragma unroll
  for (int i = 0; i < 8; ++i) a[i] = 0.f;
  int e = beg;
  for (; e + 16 <= end; e += 16){
    int n0 = col[e + q], n1 = col[e + 4 + q], n2 = col[e + 8 + q], n3 = col[e + 12 + q];
    uint4 u0 = ((const uint4*)(feat + (size_t)n0 * DIM))[s];
    uint4 u1 = ((const uint4*)(feat + (size_t)n1 * DIM))[s];
    uint4 u2 = ((const uint4*)(feat + (size_t)n2 * DIM))[s];
    uint4 u3 = ((const uint4*)(feat + (size_t)n3 * DIM))[s];
    acc8(a, u0); acc8(a, u1); acc8(a, u2); acc8(a, u3);
  }
  for (; e < end; e += 4){
    bool valid = (e + q) < end;
    int idx = valid ? (e + q) : beg;       // beg is a valid index whenever loop runs
    int nb = col[idx];
    uint4 u = ((const uint4*)(feat + (size_t)nb * DIM))[s];
    if (valid) acc8(a, u);
  }
  #pragma unroll
  for (int i = 0; i < 8; ++i){
    a[i] += __shfl_xor(a[i], 16, 64);
    a[i] += __shfl_xor(a[i], 32, 64);
  }
  if (q == 0){
    int d = end - beg;
    float r = 1.0f / (float)(d > 1 ? d : 1);
    uint4 o;
    o.x = (unsigned int)f2bf(a[0] * r) | ((unsigned int)f2bf(a[1] * r) << 16);
    o.y = (unsigned int)f2bf(a[2] * r) | ((unsigned int)f2bf(a[3] * r) << 16);
    o.z = (unsigned int)f2bf(a[4] * r) | ((unsigned int)f2bf(a[5] * r) << 16);
    o.w = (unsigned int)f2bf(a[6] * r) | ((unsigned int)f2bf(a[7] * r) << 16);
    ((uint4*)(out + (size_t)wid * DIM))[s] = o;
  }
}

// ---- f32 mean aggregation (fallback small-ws path, proven) -----------------

__global__ __launch_bounds__(256) void k_agg_f32(const float* __restrict__ feat,
    const int* __restrict__ rowptr, const int* __restrict__ col,
    unsigned short* __restrict__ out, int N){
  int wid = (blockIdx.x * 256 + threadIdx.x) >> 6;
  if (wid >= N) return;
  int lane = threadIdx.x & 63;
  int beg = rowptr[wid], end = rowptr[wid + 1];
  float a0 = 0.f, a1 = 0.f;
  int off = lane * 2;
  int e = beg;
  for (; e + 4 <= end; e += 4){
    int s0 = col[e], s1 = col[e+1], s2 = col[e+2], s3 = col[e+3];
    float2 v0 = *(const float2*)(feat + (size_t)s0 * DIM + off);
    float2 v1 = *(const float2*)(feat + (size_t)s1 * DIM + off);
    float2 v2 = *(const float2*)(feat + (size_t)s2 * DIM + off);
    float2 v3 = *(const float2*)(feat + (size_t)s3 * DIM + off);
    a0 += v0.x + v1.x + v2.x + v3.x;
    a1 += v0.y + v1.y + v2.y + v3.y;
  }
  for (; e < end; ++e){
    float2 v = *(const float2*)(feat + (size_t)col[e] * DIM + off);
    a0 += v.x; a1 += v.y;
  }
  int d = end - beg;
  float r = 1.0f / (float)(d > 1 ? d : 1);
  a0 *= r; a1 *= r;
  unsigned int o = (unsigned int)f2bf(a0) | ((unsigned int)f2bf(a1) << 16);
  *(unsigned int*)(out + (size_t)wid * DIM + off) = o;
}

// ---- fused dual GEMM: out = relu(A1@Wl + A2@Wr + bias) ---------------------

template<bool A2BF, bool OUTBF>
__global__ __launch_bounds__(256) void k_gemm(const unsigned short* __restrict__ A1,
    const float* __restrict__ A2f, const unsigned short* __restrict__ A2b,
    const float* __restrict__ Wl, const float* __restrict__ Wr,
    const float* __restrict__ bias,
    float* __restrict__ outf, unsigned short* __restrict__ outb, int M)
{
  __shared__ unsigned short lds[2 * 128 * 128];  // 64 KiB (bf16 WlT | WrT)
  for (int h = threadIdx.x; h < 128 * 128; h += 256){
    int k = h >> 7, n = h & 127;               // W[k][n]
    int idx = n * 128 + ((((k >> 3) ^ (n & 7)) << 3)) + (k & 7);
    lds[idx]         = f2bf(Wl[h]);
    lds[16384 + idx] = f2bf(Wr[h]);
  }
  __syncthreads();
  int lane = threadIdx.x & 63;
  int c = lane & 15, quad = lane >> 4;
  int gwid = blockIdx.x * 4 + (threadIdx.x >> 6);
  int nwaves = gridDim.x * 4;
  int ntasks = M >> 4;
  for (int task = gwid; task < ntasks; task += nwaves){
    int row0 = task << 4;
    floatx4 acc[8];
    #pragma unroll
    for (int j = 0; j < 8; ++j) acc[j] = (floatx4){0.f, 0.f, 0.f, 0.f};
    const unsigned short* ap1 = A1 + (size_t)(row0 + c) * DIM + quad * 8;
    #pragma unroll
    for (int km = 0; km < 4; ++km){
      short8 a = *(const short8*)(ap1 + km * 32);
      int kb = (km << 2) + quad;
      #pragma unroll
      for (int j = 0; j < 8; ++j){
        short8 b = *(const short8*)(&lds[(j * 16 + c) * 128 + ((kb ^ (c & 7)) << 3)]);
        acc[j] = __builtin_amdgcn_mfma_f32_16x16x32_bf16(a, b, acc[j], 0, 0, 0);
      }
    }
    #pragma unroll
    for (int km = 0; km < 4; ++km){
      short8 av;
      if (A2BF){
        av = *(const short8*)(A2b + (size_t)(row0 + c) * DIM + quad * 8 + km * 32);
      } else {
        const float* ap2 = A2f + (size_t)(row0 + c) * DIM + quad * 8;
        float4 p0 = *(const float4*)(ap2 + km * 32);
        float4 p1 = *(const float4*)(ap2 + km * 32 + 4);
        union { short8 v; unsigned short u[8]; } ua;
        ua.u[0] = f2bf(p0.x); ua.u[1] = f2bf(p0.y);
        ua.u[2] = f2bf(p0.z); ua.u[3] = f2bf(p0.w);
        ua.u[4] = f2bf(p1.x); ua.u[5] = f2bf(p1.y);
        ua.u[6] = f2bf(p1.z); ua.u[7] = f2bf(p1.w);
        av = ua.v;
      }
      int kb = (km << 2) + quad;
      #pragma unroll
      for (int j = 0; j < 8; ++j){
        short8 b = *(const short8*)(&lds[16384 + (j * 16 + c) * 128 + ((kb ^ (c & 7)) << 3)]);
        acc[j] = __builtin_amdgcn_mfma_f32_16x16x32_bf16(av, b, acc[j], 0, 0, 0);
      }
    }
    #pragma unroll
    for (int j = 0; j < 8; ++j){
      int colIdx = j * 16 + c;
      float bv = bias[colIdx];
      #pragma unroll
      for (int r = 0; r < 4; ++r){
        int row = row0 + quad * 4 + r;
        float v = fmaxf(acc[j][r] + bv, 0.f);
        if (OUTBF) outb[(size_t)row * DIM + colIdx] = f2bf(v);
        else       outf[(size_t)row * DIM + colIdx] = v;
      }
    }
  }
}

// ---- host ------------------------------------------------------------------

extern "C" void kernel_launch(void* const* d_in, const int* in_sizes, int n_in,
                              void* d_out, int out_size, void* d_ws, size_t ws_size,
                              hipStream_t stream)
{
  const float* x   = (const float*)d_in[0];
  const int*   ei  = (const int*)d_in[1];
  const float* Wl1 = (const float*)d_in[2];
  const float* bl1 = (const float*)d_in[3];
  const float* Wr1 = (const float*)d_in[4];
  const float* Wl2 = (const float*)d_in[5];
  const float* bl2 = (const float*)d_in[6];
  const float* Wr2 = (const float*)d_in[7];

  const int N = in_sizes[0] / DIM;
  const int E = in_sizes[1] / 2;
  const int* src  = ei;
  const int* dstI = ei + E;

  char* p = (char*)d_ws;
  auto alloc = [&](size_t bytes) -> char* {
    char* r = p; p += (bytes + 255) & ~((size_t)255); return r;
  };
  int* rowptr = (int*)alloc((size_t)(N + 1) * 4);
  int* deg    = (int*)alloc((size_t)N * 4);      // reused as cursor after scan
  int* bsum   = (int*)alloc(1024);
  int* col    = (int*)alloc((size_t)E * 4);
  unsigned short* aggb = (unsigned short*)alloc((size_t)N * DIM * 2);
  unsigned short* xb  = (unsigned short*)alloc((size_t)N * DIM * 2);
  unsigned short* h1b = (unsigned short*)alloc((size_t)N * DIM * 2);
  size_t need_big = (size_t)(p - (char*)d_ws);
  const bool big = (ws_size >= need_big);

  hipMemsetAsync(deg, 0, (size_t)N * 4, stream);

  int gE = (E + 255) / 256;
  k_hist<<<gE, 256, 0, stream>>>(dstI, E, deg);
  int nb = (N + 1023) / 1024;
  k_scan1<<<nb, 256, 0, stream>>>(deg, N, rowptr, bsum);
  k_scan2<<<1, 128, 0, stream>>>(bsum, nb);
  k_scan3<<<(N + 255) / 256, 256, 0, stream>>>(rowptr, bsum, N, E, /*cursor=*/deg);
  k_fill<<<gE, 256, 0, stream>>>(src, dstI, E, /*cursor=*/deg, col);

  int gAgg = (N * 64 + 255) / 256;  // one wave per node

  if (big){
    int n4 = N * DIM / 4;
    k_cast<<<8192, 256, 0, stream>>>(x, xb, n4);
    k_agg_bf<<<gAgg, 256, 0, stream>>>(xb, rowptr, col, aggb, N);
    k_gemm<true, true><<<512, 256, 0, stream>>>(aggb, nullptr, xb, Wl1, Wr1, bl1,
                                                nullptr, h1b, N);
    k_agg_bf<<<gAgg, 256, 0, stream>>>(h1b, rowptr, col, aggb, N);
    k_gemm<true, false><<<512, 256, 0, stream>>>(aggb, nullptr, h1b, Wl2, Wr2, bl2,
                                                 (float*)d_out, nullptr, N);
  } else {
    float* h1 = (float*)d_out;
    k_agg_f32<<<gAgg, 256, 0, stream>>>(x, rowptr, col, aggb, N);
    k_gemm<false, false><<<512, 256, 0, stream>>>(aggb, x, nullptr, Wl1, Wr1, bl1,
                                                  h1, nullptr, N);
    k_agg_f32<<<gAgg, 256, 0, stream>>>(h1, rowptr, col, aggb, N);
    k_gemm<false, false><<<512, 256, 0, stream>>>(aggb, h1, nullptr, Wl2, Wr2, bl2,
                                                  (float*)d_out, nullptr, N);
  }
}

// Round 6
// 469.123 us; speedup vs baseline: 1.7154x; 1.1422x over previous
//
#include <hip/hip_runtime.h>
#include <stdint.h>

#define DIM 128

typedef __attribute__((ext_vector_type(8))) short short8;
typedef __attribute__((ext_vector_type(4))) float floatx4;

__device__ __forceinline__ unsigned short f2bf(float f){
  union { float f; unsigned int i; } c; c.f = f;
  unsigned int u = c.i;
  return (unsigned short)((u + 0x7fffu + ((u >> 16) & 1u)) >> 16);
}
__device__ __forceinline__ float up_lo(unsigned int v){ return __uint_as_float(v << 16); }
__device__ __forceinline__ float up_hi(unsigned int v){ return __uint_as_float(v & 0xffff0000u); }

// ---- f32 -> bf16 cast ------------------------------------------------------

__global__ __launch_bounds__(256) void k_cast(const float* __restrict__ in,
    unsigned short* __restrict__ out, int n4){
  int i = blockIdx.x * 256 + threadIdx.x;
  int stride = gridDim.x * 256;
  for (; i < n4; i += stride){
    float4 v = ((const float4*)in)[i];
    ushort4 o;
    o.x = f2bf(v.x); o.y = f2bf(v.y); o.z = f2bf(v.z); o.w = f2bf(v.w);
    ((ushort4*)out)[i] = o;
  }
}

// ---- CSR build -------------------------------------------------------------

__global__ __launch_bounds__(256) void k_hist(const int* __restrict__ dst, int E,
                                              int* __restrict__ deg){
  int e = blockIdx.x * 256 + threadIdx.x;
  if (e < E) atomicAdd(&deg[dst[e]], 1);
}

__global__ __launch_bounds__(256) void k_scan1(const int* __restrict__ deg, int N,
    int* __restrict__ out, int* __restrict__ bsum){
  __shared__ int sd[256];
  int t = threadIdx.x;
  int base = blockIdx.x * 1024 + t * 4;
  int v0=0, v1=0, v2=0, v3=0;
  if (base + 3 < N) { int4 q = *(const int4*)(deg + base); v0=q.x; v1=q.y; v2=q.z; v3=q.w; }
  else {
    if (base + 0 < N) v0 = deg[base + 0];
    if (base + 1 < N) v1 = deg[base + 1];
    if (base + 2 < N) v2 = deg[base + 2];
  }
  int s = v0 + v1 + v2 + v3;
  sd[t] = s;
  __syncthreads();
  #pragma unroll
  for (int off = 1; off < 256; off <<= 1){
    int x = (t >= off) ? sd[t - off] : 0;
    __syncthreads();
    sd[t] += x;
    __syncthreads();
  }
  int inc = sd[t];
  int exc = inc - s;
  if (base + 0 < N) out[base + 0] = exc;
  if (base + 1 < N) out[base + 1] = exc + v0;
  if (base + 2 < N) out[base + 2] = exc + v0 + v1;
  if (base + 3 < N) out[base + 3] = exc + v0 + v1 + v2;
  if (t == 255) bsum[blockIdx.x] = inc;
}

__global__ __launch_bounds__(128) void k_scan2(int* __restrict__ bsum, int nb){
  __shared__ int sd[128];
  int t = threadIdx.x;
  int v = (t < nb) ? bsum[t] : 0;
  sd[t] = v;
  __syncthreads();
  #pragma unroll
  for (int off = 1; off < 128; off <<= 1){
    int x = (t >= off) ? sd[t - off] : 0;
    __syncthreads();
    sd[t] += x;
    __syncthreads();
  }
  if (t < nb) bsum[t] = sd[t] - v;
}

// finalizes rowptr, seeds per-node cursor (for fallback k_fill) and
// per-bucket base offsets (bucket = 512 consecutive nodes)
__global__ __launch_bounds__(256) void k_scan3(int* __restrict__ rowptr,
    const int* __restrict__ bsum, int N, int E, int* __restrict__ cursor,
    int* __restrict__ bucketBase){
  int i = blockIdx.x * 256 + threadIdx.x;
  if (i < N){
    int v = rowptr[i] + bsum[i >> 10];
    rowptr[i] = v;
    cursor[i] = v;
    if ((i & 511) == 0) bucketBase[i >> 9] = v;
  }
  if (i == 0) rowptr[N] = E;
}

// fallback scatter fill (small-ws path)
__global__ __launch_bounds__(256) void k_fill(const int* __restrict__ src,
    const int* __restrict__ dst, int E, int* __restrict__ cursor, int* __restrict__ col){
  int e = blockIdx.x * 256 + threadIdx.x;
  if (e < E){
    int d = dst[e];
    int pos = atomicAdd(&cursor[d], 1);
    col[pos] = src[e];
  }
}

// ---- bucketed CSR fill, pass A: bin (src,dst) pairs by dst>>9 --------------
// Each block: 4096 edges -> LDS local sort by bucket -> reserve global space
// (one atomic per touched bucket) -> flush bucket-contiguous runs.

__global__ __launch_bounds__(256) void k_bin(const int* __restrict__ src,
    const int* __restrict__ dst, int E,
    const int* __restrict__ bucketBase, int* __restrict__ cursor,
    int2* __restrict__ binned, int NB){
  __shared__ int2 buf[4096];
  __shared__ unsigned char bidArr[4096];
  __shared__ int cnt[256], startA[256], gstart[256], gbase[256];
  int t = threadIdx.x;
  cnt[t] = 0;
  if (t < NB) gbase[t] = bucketBase[t];
  __syncthreads();
  int base = blockIdx.x * 4096;
  int s_[16], d_[16], r_[16];
  #pragma unroll
  for (int i = 0; i < 16; ++i){
    int e = base + i * 256 + t;
    bool v = (e < E);
    s_[i] = v ? src[e] : 0;
    d_[i] = v ? dst[e] : -1;
    r_[i] = v ? atomicAdd(&cnt[d_[i] >> 9], 1) : 0;
  }
  __syncthreads();
  // exclusive scan of cnt -> startA
  int v = cnt[t];
  startA[t] = v;
  __syncthreads();
  #pragma unroll
  for (int off = 1; off < 256; off <<= 1){
    int y = (t >= off) ? startA[t - off] : 0;
    __syncthreads();
    startA[t] += y;
    __syncthreads();
  }
  int incl = startA[t];
  __syncthreads();
  startA[t] = incl - v;  // exclusive
  __syncthreads();
  // local scatter into LDS
  #pragma unroll
  for (int i = 0; i < 16; ++i){
    if (d_[i] >= 0){
      int b = d_[i] >> 9;
      int slot = startA[b] + r_[i];
      buf[slot] = make_int2(s_[i], d_[i]);
      bidArr[slot] = (unsigned char)b;
    }
  }
  // reserve global space per bucket
  if (cnt[t] > 0) gstart[t] = atomicAdd(&cursor[t], cnt[t]);
  __syncthreads();
  int total = startA[255] + cnt[255];
  for (int j = t; j < total; j += 256){
    int b = bidArr[j];
    binned[gbase[b] + gstart[b] + (j - startA[b])] = buf[j];
  }
}

// ---- bucketed CSR fill, pass B: one block per bucket -----------------------
// All col writes land in one contiguous ~32KB region -> full-line writebacks.

__global__ __launch_bounds__(256) void k_csr(const int2* __restrict__ binned,
    const int* __restrict__ rowptr, int N, int* __restrict__ col){
  __shared__ int rp[513];
  __shared__ int cur[512];
  int b = blockIdx.x;
  int node0 = b << 9;
  int nNodes = min(512, N - node0);
  int t = threadIdx.x;
  for (int j = t; j <= nNodes; j += 256) rp[j] = rowptr[node0 + j];
  for (int j = t; j < nNodes; j += 256) cur[j] = 0;
  __syncthreads();
  int lo = rp[0], hi = rp[nNodes];
  for (int e = lo + t; e < hi; e += 256){
    int2 pr = binned[e];
    int dl = pr.y - node0;
    int loc = atomicAdd(&cur[dl], 1);
    col[rp[dl] + loc] = pr.x;
  }
}

// ---- bf16 mean aggregation: quarter-wave row gathers -----------------------

__device__ __forceinline__ void acc8(float* a, uint4 u){
  a[0] += up_lo(u.x); a[1] += up_hi(u.x);
  a[2] += up_lo(u.y); a[3] += up_hi(u.y);
  a[4] += up_lo(u.z); a[5] += up_hi(u.z);
  a[6] += up_lo(u.w); a[7] += up_hi(u.w);
}

__global__ __launch_bounds__(256) void k_agg_bf(const unsigned short* __restrict__ feat,
    const int* __restrict__ rowptr, const int* __restrict__ col,
    unsigned short* __restrict__ out, int N){
  int wid = (blockIdx.x * 256 + threadIdx.x) >> 6;
  if (wid >= N) return;
  int lane = threadIdx.x & 63;
  int q = lane >> 4, s = lane & 15;
  int beg = rowptr[wid], end = rowptr[wid + 1];
  float a[8];
  #pragma unroll
  for (int i = 0; i < 8; ++i) a[i] = 0.f;
  int e = beg;
  for (; e + 16 <= end; e += 16){
    int n0 = col[e + q], n1 = col[e + 4 + q], n2 = col[e + 8 + q], n3 = col[e + 12 + q];
    uint4 u0 = ((const uint4*)(feat + (size_t)n0 * DIM))[s];
    uint4 u1 = ((const uint4*)(feat + (size_t)n1 * DIM))[s];
    uint4 u2 = ((const uint4*)(feat + (size_t)n2 * DIM))[s];
    uint4 u3 = ((const uint4*)(feat + (size_t)n3 * DIM))[s];
    acc8(a, u0); acc8(a, u1); acc8(a, u2); acc8(a, u3);
  }
  for (; e < end; e += 4){
    bool valid = (e + q) < end;
    int idx = valid ? (e + q) : beg;
    int nb = col[idx];
    uint4 u = ((const uint4*)(feat + (size_t)nb * DIM))[s];
    if (valid) acc8(a, u);
  }
  #pragma unroll
  for (int i = 0; i < 8; ++i){
    a[i] += __shfl_xor(a[i], 16, 64);
    a[i] += __shfl_xor(a[i], 32, 64);
  }
  if (q == 0){
    int d = end - beg;
    float r = 1.0f / (float)(d > 1 ? d : 1);
    uint4 o;
    o.x = (unsigned int)f2bf(a[0] * r) | ((unsigned int)f2bf(a[1] * r) << 16);
    o.y = (unsigned int)f2bf(a[2] * r) | ((unsigned int)f2bf(a[3] * r) << 16);
    o.z = (unsigned int)f2bf(a[4] * r) | ((unsigned int)f2bf(a[5] * r) << 16);
    o.w = (unsigned int)f2bf(a[6] * r) | ((unsigned int)f2bf(a[7] * r) << 16);
    ((uint4*)(out + (size_t)wid * DIM))[s] = o;
  }
}

// ---- f32 mean aggregation (fallback small-ws path) -------------------------

__global__ __launch_bounds__(256) void k_agg_f32(const float* __restrict__ feat,
    const int* __restrict__ rowptr, const int* __restrict__ col,
    unsigned short* __restrict__ out, int N){
  int wid = (blockIdx.x * 256 + threadIdx.x) >> 6;
  if (wid >= N) return;
  int lane = threadIdx.x & 63;
  int beg = rowptr[wid], end = rowptr[wid + 1];
  float a0 = 0.f, a1 = 0.f;
  int off = lane * 2;
  int e = beg;
  for (; e + 4 <= end; e += 4){
    int s0 = col[e], s1 = col[e+1], s2 = col[e+2], s3 = col[e+3];
    float2 v0 = *(const float2*)(feat + (size_t)s0 * DIM + off);
    float2 v1 = *(const float2*)(feat + (size_t)s1 * DIM + off);
    float2 v2 = *(const float2*)(feat + (size_t)s2 * DIM + off);
    float2 v3 = *(const float2*)(feat + (size_t)s3 * DIM + off);
    a0 += v0.x + v1.x + v2.x + v3.x;
    a1 += v0.y + v1.y + v2.y + v3.y;
  }
  for (; e < end; ++e){
    float2 v = *(const float2*)(feat + (size_t)col[e] * DIM + off);
    a0 += v.x; a1 += v.y;
  }
  int d = end - beg;
  float r = 1.0f / (float)(d > 1 ? d : 1);
  a0 *= r; a1 *= r;
  unsigned int o = (unsigned int)f2bf(a0) | ((unsigned int)f2bf(a1) << 16);
  *(unsigned int*)(out + (size_t)wid * DIM + off) = o;
}

// ---- fused dual GEMM: out = relu(A1@Wl + A2@Wr + bias) ---------------------

template<bool A2BF, bool OUTBF>
__global__ __launch_bounds__(256) void k_gemm(const unsigned short* __restrict__ A1,
    const float* __restrict__ A2f, const unsigned short* __restrict__ A2b,
    const float* __restrict__ Wl, const float* __restrict__ Wr,
    const float* __restrict__ bias,
    float* __restrict__ outf, unsigned short* __restrict__ outb, int M)
{
  __shared__ unsigned short lds[2 * 128 * 128];  // 64 KiB (bf16 WlT | WrT)
  for (int h = threadIdx.x; h < 128 * 128; h += 256){
    int k = h >> 7, n = h & 127;               // W[k][n]
    int idx = n * 128 + ((((k >> 3) ^ (n & 7)) << 3)) + (k & 7);
    lds[idx]         = f2bf(Wl[h]);
    lds[16384 + idx] = f2bf(Wr[h]);
  }
  __syncthreads();
  int lane = threadIdx.x & 63;
  int c = lane & 15, quad = lane >> 4;
  int gwid = blockIdx.x * 4 + (threadIdx.x >> 6);
  int nwaves = gridDim.x * 4;
  int ntasks = M >> 4;
  for (int task = gwid; task < ntasks; task += nwaves){
    int row0 = task << 4;
    floatx4 acc[8];
    #pragma unroll
    for (int j = 0; j < 8; ++j) acc[j] = (floatx4){0.f, 0.f, 0.f, 0.f};
    const unsigned short* ap1 = A1 + (size_t)(row0 + c) * DIM + quad * 8;
    #pragma unroll
    for (int km = 0; km < 4; ++km){
      short8 a = *(const short8*)(ap1 + km * 32);
      int kb = (km << 2) + quad;
      #pragma unroll
      for (int j = 0; j < 8; ++j){
        short8 b = *(const short8*)(&lds[(j * 16 + c) * 128 + ((kb ^ (c & 7)) << 3)]);
        acc[j] = __builtin_amdgcn_mfma_f32_16x16x32_bf16(a, b, acc[j], 0, 0, 0);
      }
    }
    #pragma unroll
    for (int km = 0; km < 4; ++km){
      short8 av;
      if (A2BF){
        av = *(const short8*)(A2b + (size_t)(row0 + c) * DIM + quad * 8 + km * 32);
      } else {
        const float* ap2 = A2f + (size_t)(row0 + c) * DIM + quad * 8;
        float4 p0 = *(const float4*)(ap2 + km * 32);
        float4 p1 = *(const float4*)(ap2 + km * 32 + 4);
        union { short8 v; unsigned short u[8]; } ua;
        ua.u[0] = f2bf(p0.x); ua.u[1] = f2bf(p0.y);
        ua.u[2] = f2bf(p0.z); ua.u[3] = f2bf(p0.w);
        ua.u[4] = f2bf(p1.x); ua.u[5] = f2bf(p1.y);
        ua.u[6] = f2bf(p1.z); ua.u[7] = f2bf(p1.w);
        av = ua.v;
      }
      int kb = (km << 2) + quad;
      #pragma unroll
      for (int j = 0; j < 8; ++j){
        short8 b = *(const short8*)(&lds[16384 + (j * 16 + c) * 128 + ((kb ^ (c & 7)) << 3)]);
        acc[j] = __builtin_amdgcn_mfma_f32_16x16x32_bf16(av, b, acc[j], 0, 0, 0);
      }
    }
    #pragma unroll
    for (int j = 0; j < 8; ++j){
      int colIdx = j * 16 + c;
      float bv = bias[colIdx];
      #pragma unroll
      for (int r = 0; r < 4; ++r){
        int row = row0 + quad * 4 + r;
        float v = fmaxf(acc[j][r] + bv, 0.f);
        if (OUTBF) outb[(size_t)row * DIM + colIdx] = f2bf(v);
        else       outf[(size_t)row * DIM + colIdx] = v;
      }
    }
  }
}

// ---- host ------------------------------------------------------------------

extern "C" void kernel_launch(void* const* d_in, const int* in_sizes, int n_in,
                              void* d_out, int out_size, void* d_ws, size_t ws_size,
                              hipStream_t stream)
{
  const float* x   = (const float*)d_in[0];
  const int*   ei  = (const int*)d_in[1];
  const float* Wl1 = (const float*)d_in[2];
  const float* bl1 = (const float*)d_in[3];
  const float* Wr1 = (const float*)d_in[4];
  const float* Wl2 = (const float*)d_in[5];
  const float* bl2 = (const float*)d_in[6];
  const float* Wr2 = (const float*)d_in[7];

  const int N = in_sizes[0] / DIM;
  const int E = in_sizes[1] / 2;
  const int* src  = ei;
  const int* dstI = ei + E;
  const int NB = (N + 511) >> 9;   // 196 for N=100000 (must be <= 256)

  char* p = (char*)d_ws;
  auto alloc = [&](size_t bytes) -> char* {
    char* r = p; p += (bytes + 255) & ~((size_t)255); return r;
  };
  int* rowptr   = (int*)alloc((size_t)(N + 1) * 4);
  int* deg      = (int*)alloc((size_t)N * 4);      // reused as cursor by k_fill
  int* bsum     = (int*)alloc(1024);
  int* bktBase  = (int*)alloc(1024);
  int* bktCur   = (int*)alloc(1024);
  int* col      = (int*)alloc((size_t)E * 4);
  unsigned short* aggb = (unsigned short*)alloc((size_t)N * DIM * 2);
  unsigned short* xb   = (unsigned short*)alloc((size_t)N * DIM * 2);
  unsigned short* h1b  = (unsigned short*)alloc((size_t)N * DIM * 2);
  size_t need_big = (size_t)(p - (char*)d_ws);
  const bool big = (ws_size >= need_big) && (NB <= 256);
  int2* binned = (int2*)aggb;  // overlays aggb: dead before first k_agg write

  hipMemsetAsync(deg, 0, (size_t)N * 4, stream);
  hipMemsetAsync(bktCur, 0, 1024, stream);

  int gE = (E + 255) / 256;
  k_hist<<<gE, 256, 0, stream>>>(dstI, E, deg);
  int nb = (N + 1023) / 1024;
  k_scan1<<<nb, 256, 0, stream>>>(deg, N, rowptr, bsum);
  k_scan2<<<1, 128, 0, stream>>>(bsum, nb);
  k_scan3<<<(N + 255) / 256, 256, 0, stream>>>(rowptr, bsum, N, E,
                                               /*cursor=*/deg, bktBase);

  int gAgg = (N * 64 + 255) / 256;  // one wave per node

  if (big){
    k_bin<<<(E + 4095) / 4096, 256, 0, stream>>>(src, dstI, E, bktBase, bktCur,
                                                 binned, NB);
    k_csr<<<NB, 256, 0, stream>>>(binned, rowptr, N, col);
    int n4 = N * DIM / 4;
    k_cast<<<8192, 256, 0, stream>>>(x, xb, n4);
    k_agg_bf<<<gAgg, 256, 0, stream>>>(xb, rowptr, col, aggb, N);
    k_gemm<true, true><<<512, 256, 0, stream>>>(aggb, nullptr, xb, Wl1, Wr1, bl1,
                                                nullptr, h1b, N);
    k_agg_bf<<<gAgg, 256, 0, stream>>>(h1b, rowptr, col, aggb, N);
    k_gemm<true, false><<<512, 256, 0, stream>>>(aggb, nullptr, h1b, Wl2, Wr2, bl2,
                                                 (float*)d_out, nullptr, N);
  } else {
    k_fill<<<gE, 256, 0, stream>>>(src, dstI, E, /*cursor=*/deg, col);
    float* h1 = (float*)d_out;
    k_agg_f32<<<gAgg, 256, 0, stream>>>(x, rowptr, col, aggb, N);
    k_gemm<false, false><<<512, 256, 0, stream>>>(aggb, x, nullptr, Wl1, Wr1, bl1,
                                                  h1, nullptr, N);
    k_agg_f32<<<gAgg, 256, 0, stream>>>(h1, rowptr, col, aggb, N);
    k_gemm<false, false><<<512, 256, 0, stream>>>(aggb, h1, nullptr, Wl2, Wr2, bl2,
                                                  (float*)d_out, nullptr, N);
  }
}

// Round 7
// 388.487 us; speedup vs baseline: 2.0715x; 1.2076x over previous
//
#include <hip/hip_runtime.h>
#include <stdint.h>

#define DIM 128

typedef __attribute__((ext_vector_type(8))) short short8;
typedef __attribute__((ext_vector_type(4))) float floatx4;

__device__ __forceinline__ unsigned short f2bf(float f){
  union { float f; unsigned int i; } c; c.f = f;
  unsigned int u = c.i;
  return (unsigned short)((u + 0x7fffu + ((u >> 16) & 1u)) >> 16);
}
__device__ __forceinline__ float up_lo(unsigned int v){ return __uint_as_float(v << 16); }
__device__ __forceinline__ float up_hi(unsigned int v){ return __uint_as_float(v & 0xffff0000u); }

// ---- f32 -> bf16 cast ------------------------------------------------------

__global__ __launch_bounds__(256) void k_cast(const float* __restrict__ in,
    unsigned short* __restrict__ out, int n4){
  int i = blockIdx.x * 256 + threadIdx.x;
  int stride = gridDim.x * 256;
  for (; i < n4; i += stride){
    float4 v = ((const float4*)in)[i];
    ushort4 o;
    o.x = f2bf(v.x); o.y = f2bf(v.y); o.z = f2bf(v.z); o.w = f2bf(v.w);
    ((ushort4*)out)[i] = o;
  }
}

// ---- CSR build -------------------------------------------------------------

__global__ __launch_bounds__(256) void k_hist(const int* __restrict__ dst, int E,
                                              int* __restrict__ deg){
  int e = blockIdx.x * 256 + threadIdx.x;
  if (e < E) atomicAdd(&deg[dst[e]], 1);
}

__global__ __launch_bounds__(256) void k_scan1(const int* __restrict__ deg, int N,
    int* __restrict__ out, int* __restrict__ bsum){
  __shared__ int sd[256];
  int t = threadIdx.x;
  int base = blockIdx.x * 1024 + t * 4;
  int v0=0, v1=0, v2=0, v3=0;
  if (base + 3 < N) { int4 q = *(const int4*)(deg + base); v0=q.x; v1=q.y; v2=q.z; v3=q.w; }
  else {
    if (base + 0 < N) v0 = deg[base + 0];
    if (base + 1 < N) v1 = deg[base + 1];
    if (base + 2 < N) v2 = deg[base + 2];
  }
  int s = v0 + v1 + v2 + v3;
  sd[t] = s;
  __syncthreads();
  #pragma unroll
  for (int off = 1; off < 256; off <<= 1){
    int x = (t >= off) ? sd[t - off] : 0;
    __syncthreads();
    sd[t] += x;
    __syncthreads();
  }
  int inc = sd[t];
  int exc = inc - s;
  if (base + 0 < N) out[base + 0] = exc;
  if (base + 1 < N) out[base + 1] = exc + v0;
  if (base + 2 < N) out[base + 2] = exc + v0 + v1;
  if (base + 3 < N) out[base + 3] = exc + v0 + v1 + v2;
  if (t == 255) bsum[blockIdx.x] = inc;
}

__global__ __launch_bounds__(128) void k_scan2(int* __restrict__ bsum, int nb){
  __shared__ int sd[128];
  int t = threadIdx.x;
  int v = (t < nb) ? bsum[t] : 0;
  sd[t] = v;
  __syncthreads();
  #pragma unroll
  for (int off = 1; off < 128; off <<= 1){
    int x = (t >= off) ? sd[t - off] : 0;
    __syncthreads();
    sd[t] += x;
    __syncthreads();
  }
  if (t < nb) bsum[t] = sd[t] - v;
}

__global__ __launch_bounds__(256) void k_scan3(int* __restrict__ rowptr,
    const int* __restrict__ bsum, int N, int E, int* __restrict__ cursor,
    int* __restrict__ bucketBase){
  int i = blockIdx.x * 256 + threadIdx.x;
  if (i < N){
    int v = rowptr[i] + bsum[i >> 10];
    rowptr[i] = v;
    cursor[i] = v;
    if ((i & 511) == 0) bucketBase[i >> 9] = v;
  }
  if (i == 0) rowptr[N] = E;
}

__global__ __launch_bounds__(256) void k_fill(const int* __restrict__ src,
    const int* __restrict__ dst, int E, int* __restrict__ cursor, int* __restrict__ col){
  int e = blockIdx.x * 256 + threadIdx.x;
  if (e < E){
    int d = dst[e];
    int pos = atomicAdd(&cursor[d], 1);
    col[pos] = src[e];
  }
}

// ---- bucketed CSR fill, pass A ---------------------------------------------

__global__ __launch_bounds__(256) void k_bin(const int* __restrict__ src,
    const int* __restrict__ dst, int E,
    const int* __restrict__ bucketBase, int* __restrict__ cursor,
    int2* __restrict__ binned, int NB){
  __shared__ int2 buf[4096];
  __shared__ unsigned char bidArr[4096];
  __shared__ int cnt[256], startA[256], gstart[256], gbase[256];
  int t = threadIdx.x;
  cnt[t] = 0;
  if (t < NB) gbase[t] = bucketBase[t];
  __syncthreads();
  int base = blockIdx.x * 4096;
  int s_[16], d_[16], r_[16];
  #pragma unroll
  for (int i = 0; i < 16; ++i){
    int e = base + i * 256 + t;
    bool v = (e < E);
    s_[i] = v ? src[e] : 0;
    d_[i] = v ? dst[e] : -1;
    r_[i] = v ? atomicAdd(&cnt[d_[i] >> 9], 1) : 0;
  }
  __syncthreads();
  int v = cnt[t];
  startA[t] = v;
  __syncthreads();
  #pragma unroll
  for (int off = 1; off < 256; off <<= 1){
    int y = (t >= off) ? startA[t - off] : 0;
    __syncthreads();
    startA[t] += y;
    __syncthreads();
  }
  int incl = startA[t];
  __syncthreads();
  startA[t] = incl - v;
  __syncthreads();
  #pragma unroll
  for (int i = 0; i < 16; ++i){
    if (d_[i] >= 0){
      int b = d_[i] >> 9;
      int slot = startA[b] + r_[i];
      buf[slot] = make_int2(s_[i], d_[i]);
      bidArr[slot] = (unsigned char)b;
    }
  }
  if (cnt[t] > 0) gstart[t] = atomicAdd(&cursor[t], cnt[t]);
  __syncthreads();
  int total = startA[255] + cnt[255];
  for (int j = t; j < total; j += 256){
    int b = bidArr[j];
    binned[gbase[b] + gstart[b] + (j - startA[b])] = buf[j];
  }
}

// ---- bucketed CSR fill, pass B ---------------------------------------------

__global__ __launch_bounds__(256) void k_csr(const int2* __restrict__ binned,
    const int* __restrict__ rowptr, int N, int* __restrict__ col){
  __shared__ int rp[513];
  __shared__ int cur[512];
  int b = blockIdx.x;
  int node0 = b << 9;
  int nNodes = min(512, N - node0);
  int t = threadIdx.x;
  for (int j = t; j <= nNodes; j += 256) rp[j] = rowptr[node0 + j];
  for (int j = t; j < nNodes; j += 256) cur[j] = 0;
  __syncthreads();
  int lo = rp[0], hi = rp[nNodes];
  for (int e = lo + t; e < hi; e += 256){
    int2 pr = binned[e];
    int dl = pr.y - node0;
    int loc = atomicAdd(&cur[dl], 1);
    col[rp[dl] + loc] = pr.x;
  }
}

// ---- bf16 mean aggregation: quarter-wave row gathers -----------------------

__device__ __forceinline__ void acc8(float* a, uint4 u){
  a[0] += up_lo(u.x); a[1] += up_hi(u.x);
  a[2] += up_lo(u.y); a[3] += up_hi(u.y);
  a[4] += up_lo(u.z); a[5] += up_hi(u.z);
  a[6] += up_lo(u.w); a[7] += up_hi(u.w);
}

__global__ __launch_bounds__(256) void k_agg_bf(const unsigned short* __restrict__ feat,
    const int* __restrict__ rowptr, const int* __restrict__ col,
    unsigned short* __restrict__ out, int N){
  int wid = (blockIdx.x * 256 + threadIdx.x) >> 6;
  if (wid >= N) return;
  int lane = threadIdx.x & 63;
  int q = lane >> 4, s = lane & 15;
  int beg = rowptr[wid], end = rowptr[wid + 1];
  float a[8];
  #pragma unroll
  for (int i = 0; i < 8; ++i) a[i] = 0.f;
  int e = beg;
  for (; e + 16 <= end; e += 16){
    int n0 = col[e + q], n1 = col[e + 4 + q], n2 = col[e + 8 + q], n3 = col[e + 12 + q];
    uint4 u0 = ((const uint4*)(feat + (size_t)n0 * DIM))[s];
    uint4 u1 = ((const uint4*)(feat + (size_t)n1 * DIM))[s];
    uint4 u2 = ((const uint4*)(feat + (size_t)n2 * DIM))[s];
    uint4 u3 = ((const uint4*)(feat + (size_t)n3 * DIM))[s];
    acc8(a, u0); acc8(a, u1); acc8(a, u2); acc8(a, u3);
  }
  for (; e < end; e += 4){
    bool valid = (e + q) < end;
    int idx = valid ? (e + q) : beg;
    int nb = col[idx];
    uint4 u = ((const uint4*)(feat + (size_t)nb * DIM))[s];
    if (valid) acc8(a, u);
  }
  #pragma unroll
  for (int i = 0; i < 8; ++i){
    a[i] += __shfl_xor(a[i], 16, 64);
    a[i] += __shfl_xor(a[i], 32, 64);
  }
  if (q == 0){
    int d = end - beg;
    float r = 1.0f / (float)(d > 1 ? d : 1);
    uint4 o;
    o.x = (unsigned int)f2bf(a[0] * r) | ((unsigned int)f2bf(a[1] * r) << 16);
    o.y = (unsigned int)f2bf(a[2] * r) | ((unsigned int)f2bf(a[3] * r) << 16);
    o.z = (unsigned int)f2bf(a[4] * r) | ((unsigned int)f2bf(a[5] * r) << 16);
    o.w = (unsigned int)f2bf(a[6] * r) | ((unsigned int)f2bf(a[7] * r) << 16);
    ((uint4*)(out + (size_t)wid * DIM))[s] = o;
  }
}

// ---- f32 mean aggregation (fallback small-ws path) -------------------------

__global__ __launch_bounds__(256) void k_agg_f32(const float* __restrict__ feat,
    const int* __restrict__ rowptr, const int* __restrict__ col,
    unsigned short* __restrict__ out, int N){
  int wid = (blockIdx.x * 256 + threadIdx.x) >> 6;
  if (wid >= N) return;
  int lane = threadIdx.x & 63;
  int beg = rowptr[wid], end = rowptr[wid + 1];
  float a0 = 0.f, a1 = 0.f;
  int off = lane * 2;
  int e = beg;
  for (; e + 4 <= end; e += 4){
    int s0 = col[e], s1 = col[e+1], s2 = col[e+2], s3 = col[e+3];
    float2 v0 = *(const float2*)(feat + (size_t)s0 * DIM + off);
    float2 v1 = *(const float2*)(feat + (size_t)s1 * DIM + off);
    float2 v2 = *(const float2*)(feat + (size_t)s2 * DIM + off);
    float2 v3 = *(const float2*)(feat + (size_t)s3 * DIM + off);
    a0 += v0.x + v1.x + v2.x + v3.x;
    a1 += v0.y + v1.y + v2.y + v3.y;
  }
  for (; e < end; ++e){
    float2 v = *(const float2*)(feat + (size_t)col[e] * DIM + off);
    a0 += v.x; a1 += v.y;
  }
  int d = end - beg;
  float r = 1.0f / (float)(d > 1 ? d : 1);
  a0 *= r; a1 *= r;
  unsigned int o = (unsigned int)f2bf(a0) | ((unsigned int)f2bf(a1) << 16);
  *(unsigned int*)(out + (size_t)wid * DIM + off) = o;
}

// ---- B-stationary register GEMM: out = relu(A1@Wl + A2@Wr + bias) ----------
// No LDS. Each wave owns 16 rows x 64 cols (half = gwid&1). B-fragments for
// its col-half (2 W x 4 km x 4 j = 32 frags = 128 VGPRs) are loaded once from
// the L2-resident weights, then the task loop is: 8 a-loads -> 32 MFMA ->
// stores. Mapping identical to the verified LDS path: b[i] = W[kb*8+i][n].

template<bool OUTBF>
__global__ __launch_bounds__(256) void k_gemm_r(const unsigned short* __restrict__ A1,
    const unsigned short* __restrict__ A2,
    const float* __restrict__ Wl, const float* __restrict__ Wr,
    const float* __restrict__ bias,
    float* __restrict__ outf, unsigned short* __restrict__ outb, int M)
{
  int lane = threadIdx.x & 63;
  int c = lane & 15, quad = lane >> 4;
  int gwid = blockIdx.x * 4 + (threadIdx.x >> 6);
  int nwaves = gridDim.x * 4;
  int half = gwid & 1;
  int colbase = half * 64;

  short8 B[2][4][4];   // [w][km][j] : 128 VGPRs
  #pragma unroll
  for (int w = 0; w < 2; ++w){
    const float* W = w ? Wr : Wl;
    #pragma unroll
    for (int km = 0; km < 4; ++km){
      #pragma unroll
      for (int j = 0; j < 4; ++j){
        union { short8 v; unsigned short u[8]; } tb;
        #pragma unroll
        for (int i = 0; i < 8; ++i)
          tb.u[i] = f2bf(W[(km * 32 + quad * 8 + i) * 128 + colbase + j * 16 + c]);
        B[w][km][j] = tb.v;
      }
    }
  }
  float bv[4];
  #pragma unroll
  for (int j = 0; j < 4; ++j) bv[j] = bias[colbase + j * 16 + c];

  int ntasks = M >> 4;
  for (int task = gwid >> 1; task < ntasks; task += nwaves >> 1){
    int row0 = task << 4;
    const unsigned short* ap1 = A1 + (size_t)(row0 + c) * DIM + quad * 8;
    const unsigned short* ap2 = A2 + (size_t)(row0 + c) * DIM + quad * 8;
    short8 a1[4], a2[4];
    #pragma unroll
    for (int km = 0; km < 4; ++km){
      a1[km] = *(const short8*)(ap1 + km * 32);
      a2[km] = *(const short8*)(ap2 + km * 32);
    }
    floatx4 acc[4];
    #pragma unroll
    for (int j = 0; j < 4; ++j) acc[j] = (floatx4){0.f, 0.f, 0.f, 0.f};
    #pragma unroll
    for (int km = 0; km < 4; ++km){
      #pragma unroll
      for (int j = 0; j < 4; ++j){
        acc[j] = __builtin_amdgcn_mfma_f32_16x16x32_bf16(a1[km], B[0][km][j], acc[j], 0, 0, 0);
        acc[j] = __builtin_amdgcn_mfma_f32_16x16x32_bf16(a2[km], B[1][km][j], acc[j], 0, 0, 0);
      }
    }
    #pragma unroll
    for (int j = 0; j < 4; ++j){
      int colIdx = colbase + j * 16 + c;
      #pragma unroll
      for (int r = 0; r < 4; ++r){
        int row = row0 + quad * 4 + r;
        float v = fmaxf(acc[j][r] + bv[j], 0.f);
        if (OUTBF) outb[(size_t)row * DIM + colIdx] = f2bf(v);
        else       outf[(size_t)row * DIM + colIdx] = v;
      }
    }
  }
}

// ---- fallback LDS GEMM (small-ws path, f32 A2/out) -------------------------

__global__ __launch_bounds__(256) void k_gemm_f(const unsigned short* __restrict__ A1,
    const float* __restrict__ A2f,
    const float* __restrict__ Wl, const float* __restrict__ Wr,
    const float* __restrict__ bias, float* __restrict__ outf, int M)
{
  __shared__ unsigned short lds[2 * 128 * 128];
  for (int h = threadIdx.x; h < 128 * 128; h += 256){
    int k = h >> 7, n = h & 127;
    int idx = n * 128 + ((((k >> 3) ^ (n & 7)) << 3)) + (k & 7);
    lds[idx]         = f2bf(Wl[h]);
    lds[16384 + idx] = f2bf(Wr[h]);
  }
  __syncthreads();
  int lane = threadIdx.x & 63;
  int c = lane & 15, quad = lane >> 4;
  int gwid = blockIdx.x * 4 + (threadIdx.x >> 6);
  int nwaves = gridDim.x * 4;
  int ntasks = M >> 4;
  for (int task = gwid; task < ntasks; task += nwaves){
    int row0 = task << 4;
    floatx4 acc[8];
    #pragma unroll
    for (int j = 0; j < 8; ++j) acc[j] = (floatx4){0.f, 0.f, 0.f, 0.f};
    const unsigned short* ap1 = A1 + (size_t)(row0 + c) * DIM + quad * 8;
    #pragma unroll
    for (int km = 0; km < 4; ++km){
      short8 a = *(const short8*)(ap1 + km * 32);
      int kb = (km << 2) + quad;
      #pragma unroll
      for (int j = 0; j < 8; ++j){
        short8 b = *(const short8*)(&lds[(j * 16 + c) * 128 + ((kb ^ (c & 7)) << 3)]);
        acc[j] = __builtin_amdgcn_mfma_f32_16x16x32_bf16(a, b, acc[j], 0, 0, 0);
      }
    }
    #pragma unroll
    for (int km = 0; km < 4; ++km){
      const float* ap2 = A2f + (size_t)(row0 + c) * DIM + quad * 8;
      float4 p0 = *(const float4*)(ap2 + km * 32);
      float4 p1 = *(const float4*)(ap2 + km * 32 + 4);
      union { short8 v; unsigned short u[8]; } ua;
      ua.u[0] = f2bf(p0.x); ua.u[1] = f2bf(p0.y);
      ua.u[2] = f2bf(p0.z); ua.u[3] = f2bf(p0.w);
      ua.u[4] = f2bf(p1.x); ua.u[5] = f2bf(p1.y);
      ua.u[6] = f2bf(p1.z); ua.u[7] = f2bf(p1.w);
      int kb = (km << 2) + quad;
      #pragma unroll
      for (int j = 0; j < 8; ++j){
        short8 b = *(const short8*)(&lds[16384 + (j * 16 + c) * 128 + ((kb ^ (c & 7)) << 3)]);
        acc[j] = __builtin_amdgcn_mfma_f32_16x16x32_bf16(ua.v, b, acc[j], 0, 0, 0);
      }
    }
    #pragma unroll
    for (int j = 0; j < 8; ++j){
      int colIdx = j * 16 + c;
      float bvv = bias[colIdx];
      #pragma unroll
      for (int r = 0; r < 4; ++r){
        int row = row0 + quad * 4 + r;
        outf[(size_t)row * DIM + colIdx] = fmaxf(acc[j][r] + bvv, 0.f);
      }
    }
  }
}

// ---- host ------------------------------------------------------------------

extern "C" void kernel_launch(void* const* d_in, const int* in_sizes, int n_in,
                              void* d_out, int out_size, void* d_ws, size_t ws_size,
                              hipStream_t stream)
{
  const float* x   = (const float*)d_in[0];
  const int*   ei  = (const int*)d_in[1];
  const float* Wl1 = (const float*)d_in[2];
  const float* bl1 = (const float*)d_in[3];
  const float* Wr1 = (const float*)d_in[4];
  const float* Wl2 = (const float*)d_in[5];
  const float* bl2 = (const float*)d_in[6];
  const float* Wr2 = (const float*)d_in[7];

  const int N = in_sizes[0] / DIM;
  const int E = in_sizes[1] / 2;
  const int* src  = ei;
  const int* dstI = ei + E;
  const int NB = (N + 511) >> 9;

  char* p = (char*)d_ws;
  auto alloc = [&](size_t bytes) -> char* {
    char* r = p; p += (bytes + 255) & ~((size_t)255); return r;
  };
  int* rowptr   = (int*)alloc((size_t)(N + 1) * 4);
  int* deg      = (int*)alloc((size_t)N * 4);
  int* bsum     = (int*)alloc(1024);
  int* bktBase  = (int*)alloc(1024);
  int* bktCur   = (int*)alloc(1024);
  int* col      = (int*)alloc((size_t)E * 4);
  unsigned short* aggb = (unsigned short*)alloc((size_t)N * DIM * 2);
  unsigned short* xb   = (unsigned short*)alloc((size_t)N * DIM * 2);
  unsigned short* h1b  = (unsigned short*)alloc((size_t)N * DIM * 2);
  size_t need_big = (size_t)(p - (char*)d_ws);
  const bool big = (ws_size >= need_big) && (NB <= 256);
  int2* binned = (int2*)aggb;

  hipMemsetAsync(deg, 0, (size_t)N * 4, stream);
  hipMemsetAsync(bktCur, 0, 1024, stream);

  int gE = (E + 255) / 256;
  k_hist<<<gE, 256, 0, stream>>>(dstI, E, deg);
  int nb = (N + 1023) / 1024;
  k_scan1<<<nb, 256, 0, stream>>>(deg, N, rowptr, bsum);
  k_scan2<<<1, 128, 0, stream>>>(bsum, nb);
  k_scan3<<<(N + 255) / 256, 256, 0, stream>>>(rowptr, bsum, N, E,
                                               /*cursor=*/deg, bktBase);

  int gAgg = (N * 64 + 255) / 256;

  if (big){
    k_bin<<<(E + 4095) / 4096, 256, 0, stream>>>(src, dstI, E, bktBase, bktCur,
                                                 binned, NB);
    k_csr<<<NB, 256, 0, stream>>>(binned, rowptr, N, col);
    int n4 = N * DIM / 4;
    k_cast<<<8192, 256, 0, stream>>>(x, xb, n4);
    k_agg_bf<<<gAgg, 256, 0, stream>>>(xb, rowptr, col, aggb, N);
    k_gemm_r<true><<<512, 256, 0, stream>>>(aggb, xb, Wl1, Wr1, bl1,
                                            nullptr, h1b, N);
    k_agg_bf<<<gAgg, 256, 0, stream>>>(h1b, rowptr, col, aggb, N);
    k_gemm_r<false><<<512, 256, 0, stream>>>(aggb, h1b, Wl2, Wr2, bl2,
                                             (float*)d_out, nullptr, N);
  } else {
    k_fill<<<gE, 256, 0, stream>>>(src, dstI, E, /*cursor=*/deg, col);
    float* h1 = (float*)d_out;
    k_agg_f32<<<gAgg, 256, 0, stream>>>(x, rowptr, col, aggb, N);
    k_gemm_f<<<512, 256, 0, stream>>>(aggb, x, Wl1, Wr1, bl1, h1, N);
    k_agg_f32<<<gAgg, 256, 0, stream>>>(h1, rowptr, col, aggb, N);
    k_gemm_f<<<512, 256, 0, stream>>>(aggb, h1, Wl2, Wr2, bl2, (float*)d_out, N);
  }
}

// Round 8
// 348.124 us; speedup vs baseline: 2.3116x; 1.1159x over previous
//
#include <hip/hip_runtime.h>
#include <stdint.h>

#define DIM 128

typedef __attribute__((ext_vector_type(8))) short short8;
typedef __attribute__((ext_vector_type(4))) float floatx4;

__device__ __forceinline__ unsigned short f2bf(float f){
  union { float f; unsigned int i; } c; c.f = f;
  unsigned int u = c.i;
  return (unsigned short)((u + 0x7fffu + ((u >> 16) & 1u)) >> 16);
}
__device__ __forceinline__ float up_lo(unsigned int v){ return __uint_as_float(v << 16); }
__device__ __forceinline__ float up_hi(unsigned int v){ return __uint_as_float(v & 0xffff0000u); }

// ---- f32 -> bf16 cast ------------------------------------------------------

__global__ __launch_bounds__(256) void k_cast(const float* __restrict__ in,
    unsigned short* __restrict__ out, int n4){
  int i = blockIdx.x * 256 + threadIdx.x;
  int stride = gridDim.x * 256;
  for (; i < n4; i += stride){
    float4 v = ((const float4*)in)[i];
    ushort4 o;
    o.x = f2bf(v.x); o.y = f2bf(v.y); o.z = f2bf(v.z); o.w = f2bf(v.w);
    ((ushort4*)out)[i] = o;
  }
}

// ---- bucket-grained histogram (196 counters, LDS-staged) -------------------

__global__ __launch_bounds__(256) void k_hist256(const int* __restrict__ dst, int E,
    int* __restrict__ bktCnt){
  __shared__ int h[256];
  h[threadIdx.x] = 0;
  __syncthreads();
  int i = blockIdx.x * 256 + threadIdx.x;
  int stride = gridDim.x * 256;
  for (; i < E; i += stride) atomicAdd(&h[dst[i] >> 9], 1);
  __syncthreads();
  int v = h[threadIdx.x];
  if (v) atomicAdd(&bktCnt[threadIdx.x], v);
}

// one-block exclusive scan of bucket counts; bktBase[t>=NB] = E (total)
__global__ __launch_bounds__(256) void k_scanB(const int* __restrict__ bktCnt,
    int* __restrict__ bktBase, int NB){
  __shared__ int sd[256];
  int t = threadIdx.x;
  int v = (t < NB) ? bktCnt[t] : 0;
  sd[t] = v;
  __syncthreads();
  #pragma unroll
  for (int off = 1; off < 256; off <<= 1){
    int x = (t >= off) ? sd[t - off] : 0;
    __syncthreads();
    sd[t] += x;
    __syncthreads();
  }
  bktBase[t] = sd[t] - v;   // exclusive; entries >= NB hold total E
}

// ---- legacy CSR build (fallback small-ws path) -----------------------------

__global__ __launch_bounds__(256) void k_hist(const int* __restrict__ dst, int E,
                                              int* __restrict__ deg){
  int e = blockIdx.x * 256 + threadIdx.x;
  if (e < E) atomicAdd(&deg[dst[e]], 1);
}

__global__ __launch_bounds__(256) void k_scan1(const int* __restrict__ deg, int N,
    int* __restrict__ out, int* __restrict__ bsum){
  __shared__ int sd[256];
  int t = threadIdx.x;
  int base = blockIdx.x * 1024 + t * 4;
  int v0=0, v1=0, v2=0, v3=0;
  if (base + 3 < N) { int4 q = *(const int4*)(deg + base); v0=q.x; v1=q.y; v2=q.z; v3=q.w; }
  else {
    if (base + 0 < N) v0 = deg[base + 0];
    if (base + 1 < N) v1 = deg[base + 1];
    if (base + 2 < N) v2 = deg[base + 2];
  }
  int s = v0 + v1 + v2 + v3;
  sd[t] = s;
  __syncthreads();
  #pragma unroll
  for (int off = 1; off < 256; off <<= 1){
    int x = (t >= off) ? sd[t - off] : 0;
    __syncthreads();
    sd[t] += x;
    __syncthreads();
  }
  int inc = sd[t];
  int exc = inc - s;
  if (base + 0 < N) out[base + 0] = exc;
  if (base + 1 < N) out[base + 1] = exc + v0;
  if (base + 2 < N) out[base + 2] = exc + v0 + v1;
  if (base + 3 < N) out[base + 3] = exc + v0 + v1 + v2;
  if (t == 255) bsum[blockIdx.x] = inc;
}

__global__ __launch_bounds__(128) void k_scan2(int* __restrict__ bsum, int nb){
  __shared__ int sd[128];
  int t = threadIdx.x;
  int v = (t < nb) ? bsum[t] : 0;
  sd[t] = v;
  __syncthreads();
  #pragma unroll
  for (int off = 1; off < 128; off <<= 1){
    int x = (t >= off) ? sd[t - off] : 0;
    __syncthreads();
    sd[t] += x;
    __syncthreads();
  }
  if (t < nb) bsum[t] = sd[t] - v;
}

__global__ __launch_bounds__(256) void k_scan3(int* __restrict__ rowptr,
    const int* __restrict__ bsum, int N, int E, int* __restrict__ cursor){
  int i = blockIdx.x * 256 + threadIdx.x;
  if (i < N){
    int v = rowptr[i] + bsum[i >> 10];
    rowptr[i] = v;
    cursor[i] = v;
  }
  if (i == 0) rowptr[N] = E;
}

__global__ __launch_bounds__(256) void k_fill(const int* __restrict__ src,
    const int* __restrict__ dst, int E, int* __restrict__ cursor, int* __restrict__ col){
  int e = blockIdx.x * 256 + threadIdx.x;
  if (e < E){
    int d = dst[e];
    int pos = atomicAdd(&cursor[d], 1);
    col[pos] = src[e];
  }
}

// ---- bucketed CSR fill, pass A: bin (src,dst) by dst>>9 --------------------

__global__ __launch_bounds__(256) void k_bin(const int* __restrict__ src,
    const int* __restrict__ dst, int E,
    const int* __restrict__ bucketBase, int* __restrict__ cursor,
    int2* __restrict__ binned, int NB){
  __shared__ int2 buf[4096];
  __shared__ unsigned char bidArr[4096];
  __shared__ int cnt[256], startA[256], gstart[256], gbase[256];
  int t = threadIdx.x;
  cnt[t] = 0;
  if (t < NB) gbase[t] = bucketBase[t];
  __syncthreads();
  int base = blockIdx.x * 4096;
  int s_[16], d_[16], r_[16];
  #pragma unroll
  for (int i = 0; i < 16; ++i){
    int e = base + i * 256 + t;
    bool v = (e < E);
    s_[i] = v ? src[e] : 0;
    d_[i] = v ? dst[e] : -1;
    r_[i] = v ? atomicAdd(&cnt[d_[i] >> 9], 1) : 0;
  }
  __syncthreads();
  int v = cnt[t];
  startA[t] = v;
  __syncthreads();
  #pragma unroll
  for (int off = 1; off < 256; off <<= 1){
    int y = (t >= off) ? startA[t - off] : 0;
    __syncthreads();
    startA[t] += y;
    __syncthreads();
  }
  int incl = startA[t];
  __syncthreads();
  startA[t] = incl - v;
  __syncthreads();
  #pragma unroll
  for (int i = 0; i < 16; ++i){
    if (d_[i] >= 0){
      int b = d_[i] >> 9;
      int slot = startA[b] + r_[i];
      buf[slot] = make_int2(s_[i], d_[i]);
      bidArr[slot] = (unsigned char)b;
    }
  }
  if (cnt[t] > 0) gstart[t] = atomicAdd(&cursor[t], cnt[t]);
  __syncthreads();
  int total = startA[255] + cnt[255];
  for (int j = t; j < total; j += 256){
    int b = bidArr[j];
    binned[gbase[b] + gstart[b] + (j - startA[b])] = buf[j];
  }
}

// ---- bucketed CSR fill, pass B: local degrees + scan + rowptr + scatter ----
// One block per bucket. Computes the bucket's 512 node degrees from binned,
// scans locally, writes its rowptr slice, then scatters col. All writes land
// in contiguous regions -> full-line writebacks; no global histogram needed.

__global__ __launch_bounds__(256) void k_csr2(const int2* __restrict__ binned,
    const int* __restrict__ bktBase, int N, int* __restrict__ rowptr,
    int* __restrict__ col){
  __shared__ int cnt[512], excl[512], cur[512];
  __shared__ int sd[256];
  int b = blockIdx.x;
  int node0 = b << 9;
  int nNodes = min(512, N - node0);
  int t = threadIdx.x;
  cnt[t] = 0; cnt[t + 256] = 0;
  __syncthreads();
  int lo = bktBase[b], hi = bktBase[b + 1];
  for (int e = lo + t; e < hi; e += 256)
    atomicAdd(&cnt[binned[e].y - node0], 1);
  __syncthreads();
  int c0 = cnt[2 * t], c1 = cnt[2 * t + 1];
  int ps = c0 + c1;
  sd[t] = ps;
  __syncthreads();
  #pragma unroll
  for (int off = 1; off < 256; off <<= 1){
    int x = (t >= off) ? sd[t - off] : 0;
    __syncthreads();
    sd[t] += x;
    __syncthreads();
  }
  int pexcl = sd[t] - ps;
  excl[2 * t] = pexcl;
  excl[2 * t + 1] = pexcl + c0;
  cur[2 * t] = 0; cur[2 * t + 1] = 0;
  __syncthreads();
  for (int j = t; j < nNodes; j += 256) rowptr[node0 + j] = lo + excl[j];
  if (t == 0) rowptr[node0 + nNodes] = hi;  // dup of next bucket's base: same value
  for (int e = lo + t; e < hi; e += 256){
    int2 pr = binned[e];
    int dl = pr.y - node0;
    int loc = atomicAdd(&cur[dl], 1);
    col[lo + excl[dl] + loc] = pr.x;
  }
}

// ---- bf16 mean aggregation: quarter-wave row gathers -----------------------

__device__ __forceinline__ void acc8(float* a, uint4 u){
  a[0] += up_lo(u.x); a[1] += up_hi(u.x);
  a[2] += up_lo(u.y); a[3] += up_hi(u.y);
  a[4] += up_lo(u.z); a[5] += up_hi(u.z);
  a[6] += up_lo(u.w); a[7] += up_hi(u.w);
}

__global__ __launch_bounds__(256) void k_agg_bf(const unsigned short* __restrict__ feat,
    const int* __restrict__ rowptr, const int* __restrict__ col,
    unsigned short* __restrict__ out, int N){
  int wid = (blockIdx.x * 256 + threadIdx.x) >> 6;
  if (wid >= N) return;
  int lane = threadIdx.x & 63;
  int q = lane >> 4, s = lane & 15;
  int beg = rowptr[wid], end = rowptr[wid + 1];
  float a[8];
  #pragma unroll
  for (int i = 0; i < 8; ++i) a[i] = 0.f;
  int e = beg;
  for (; e + 16 <= end; e += 16){
    int n0 = col[e + q], n1 = col[e + 4 + q], n2 = col[e + 8 + q], n3 = col[e + 12 + q];
    uint4 u0 = ((const uint4*)(feat + (size_t)n0 * DIM))[s];
    uint4 u1 = ((const uint4*)(feat + (size_t)n1 * DIM))[s];
    uint4 u2 = ((const uint4*)(feat + (size_t)n2 * DIM))[s];
    uint4 u3 = ((const uint4*)(feat + (size_t)n3 * DIM))[s];
    acc8(a, u0); acc8(a, u1); acc8(a, u2); acc8(a, u3);
  }
  for (; e < end; e += 4){
    bool valid = (e + q) < end;
    int idx = valid ? (e + q) : beg;
    int nb = col[idx];
    uint4 u = ((const uint4*)(feat + (size_t)nb * DIM))[s];
    if (valid) acc8(a, u);
  }
  #pragma unroll
  for (int i = 0; i < 8; ++i){
    a[i] += __shfl_xor(a[i], 16, 64);
    a[i] += __shfl_xor(a[i], 32, 64);
  }
  if (q == 0){
    int d = end - beg;
    float r = 1.0f / (float)(d > 1 ? d : 1);
    uint4 o;
    o.x = (unsigned int)f2bf(a[0] * r) | ((unsigned int)f2bf(a[1] * r) << 16);
    o.y = (unsigned int)f2bf(a[2] * r) | ((unsigned int)f2bf(a[3] * r) << 16);
    o.z = (unsigned int)f2bf(a[4] * r) | ((unsigned int)f2bf(a[5] * r) << 16);
    o.w = (unsigned int)f2bf(a[6] * r) | ((unsigned int)f2bf(a[7] * r) << 16);
    ((uint4*)(out + (size_t)wid * DIM))[s] = o;
  }
}

// ---- f32 mean aggregation (fallback small-ws path) -------------------------

__global__ __launch_bounds__(256) void k_agg_f32(const float* __restrict__ feat,
    const int* __restrict__ rowptr, const int* __restrict__ col,
    unsigned short* __restrict__ out, int N){
  int wid = (blockIdx.x * 256 + threadIdx.x) >> 6;
  if (wid >= N) return;
  int lane = threadIdx.x & 63;
  int beg = rowptr[wid], end = rowptr[wid + 1];
  float a0 = 0.f, a1 = 0.f;
  int off = lane * 2;
  int e = beg;
  for (; e + 4 <= end; e += 4){
    int s0 = col[e], s1 = col[e+1], s2 = col[e+2], s3 = col[e+3];
    float2 v0 = *(const float2*)(feat + (size_t)s0 * DIM + off);
    float2 v1 = *(const float2*)(feat + (size_t)s1 * DIM + off);
    float2 v2 = *(const float2*)(feat + (size_t)s2 * DIM + off);
    float2 v3 = *(const float2*)(feat + (size_t)s3 * DIM + off);
    a0 += v0.x + v1.x + v2.x + v3.x;
    a1 += v0.y + v1.y + v2.y + v3.y;
  }
  for (; e < end; ++e){
    float2 v = *(const float2*)(feat + (size_t)col[e] * DIM + off);
    a0 += v.x; a1 += v.y;
  }
  int d = end - beg;
  float r = 1.0f / (float)(d > 1 ? d : 1);
  a0 *= r; a1 *= r;
  unsigned int o = (unsigned int)f2bf(a0) | ((unsigned int)f2bf(a1) << 16);
  *(unsigned int*)(out + (size_t)wid * DIM + off) = o;
}

// ---- B-stationary register GEMM: out = relu(A1@Wl + A2@Wr + bias) ----------

template<bool OUTBF>
__global__ __launch_bounds__(256) void k_gemm_r(const unsigned short* __restrict__ A1,
    const unsigned short* __restrict__ A2,
    const float* __restrict__ Wl, const float* __restrict__ Wr,
    const float* __restrict__ bias,
    float* __restrict__ outf, unsigned short* __restrict__ outb, int M)
{
  int lane = threadIdx.x & 63;
  int c = lane & 15, quad = lane >> 4;
  int gwid = blockIdx.x * 4 + (threadIdx.x >> 6);
  int nwaves = gridDim.x * 4;
  int half = gwid & 1;
  int colbase = half * 64;

  short8 B[2][4][4];
  #pragma unroll
  for (int w = 0; w < 2; ++w){
    const float* W = w ? Wr : Wl;
    #pragma unroll
    for (int km = 0; km < 4; ++km){
      #pragma unroll
      for (int j = 0; j < 4; ++j){
        union { short8 v; unsigned short u[8]; } tb;
        #pragma unroll
        for (int i = 0; i < 8; ++i)
          tb.u[i] = f2bf(W[(km * 32 + quad * 8 + i) * 128 + colbase + j * 16 + c]);
        B[w][km][j] = tb.v;
      }
    }
  }
  float bv[4];
  #pragma unroll
  for (int j = 0; j < 4; ++j) bv[j] = bias[colbase + j * 16 + c];

  int ntasks = M >> 4;
  for (int task = gwid >> 1; task < ntasks; task += nwaves >> 1){
    int row0 = task << 4;
    const unsigned short* ap1 = A1 + (size_t)(row0 + c) * DIM + quad * 8;
    const unsigned short* ap2 = A2 + (size_t)(row0 + c) * DIM + quad * 8;
    short8 a1[4], a2[4];
    #pragma unroll
    for (int km = 0; km < 4; ++km){
      a1[km] = *(const short8*)(ap1 + km * 32);
      a2[km] = *(const short8*)(ap2 + km * 32);
    }
    floatx4 acc[4];
    #pragma unroll
    for (int j = 0; j < 4; ++j) acc[j] = (floatx4){0.f, 0.f, 0.f, 0.f};
    #pragma unroll
    for (int km = 0; km < 4; ++km){
      #pragma unroll
      for (int j = 0; j < 4; ++j){
        acc[j] = __builtin_amdgcn_mfma_f32_16x16x32_bf16(a1[km], B[0][km][j], acc[j], 0, 0, 0);
        acc[j] = __builtin_amdgcn_mfma_f32_16x16x32_bf16(a2[km], B[1][km][j], acc[j], 0, 0, 0);
      }
    }
    #pragma unroll
    for (int j = 0; j < 4; ++j){
      int colIdx = colbase + j * 16 + c;
      #pragma unroll
      for (int r = 0; r < 4; ++r){
        int row = row0 + quad * 4 + r;
        float v = fmaxf(acc[j][r] + bv[j], 0.f);
        if (OUTBF) outb[(size_t)row * DIM + colIdx] = f2bf(v);
        else       outf[(size_t)row * DIM + colIdx] = v;
      }
    }
  }
}

// ---- fallback LDS GEMM (small-ws path, f32 A2/out) -------------------------

__global__ __launch_bounds__(256) void k_gemm_f(const unsigned short* __restrict__ A1,
    const float* __restrict__ A2f,
    const float* __restrict__ Wl, const float* __restrict__ Wr,
    const float* __restrict__ bias, float* __restrict__ outf, int M)
{
  __shared__ unsigned short lds[2 * 128 * 128];
  for (int h = threadIdx.x; h < 128 * 128; h += 256){
    int k = h >> 7, n = h & 127;
    int idx = n * 128 + ((((k >> 3) ^ (n & 7)) << 3)) + (k & 7);
    lds[idx]         = f2bf(Wl[h]);
    lds[16384 + idx] = f2bf(Wr[h]);
  }
  __syncthreads();
  int lane = threadIdx.x & 63;
  int c = lane & 15, quad = lane >> 4;
  int gwid = blockIdx.x * 4 + (threadIdx.x >> 6);
  int nwaves = gridDim.x * 4;
  int ntasks = M >> 4;
  for (int task = gwid; task < ntasks; task += nwaves){
    int row0 = task << 4;
    floatx4 acc[8];
    #pragma unroll
    for (int j = 0; j < 8; ++j) acc[j] = (floatx4){0.f, 0.f, 0.f, 0.f};
    const unsigned short* ap1 = A1 + (size_t)(row0 + c) * DIM + quad * 8;
    #pragma unroll
    for (int km = 0; km < 4; ++km){
      short8 a = *(const short8*)(ap1 + km * 32);
      int kb = (km << 2) + quad;
      #pragma unroll
      for (int j = 0; j < 8; ++j){
        short8 b = *(const short8*)(&lds[(j * 16 + c) * 128 + ((kb ^ (c & 7)) << 3)]);
        acc[j] = __builtin_amdgcn_mfma_f32_16x16x32_bf16(a, b, acc[j], 0, 0, 0);
      }
    }
    #pragma unroll
    for (int km = 0; km < 4; ++km){
      const float* ap2 = A2f + (size_t)(row0 + c) * DIM + quad * 8;
      float4 p0 = *(const float4*)(ap2 + km * 32);
      float4 p1 = *(const float4*)(ap2 + km * 32 + 4);
      union { short8 v; unsigned short u[8]; } ua;
      ua.u[0] = f2bf(p0.x); ua.u[1] = f2bf(p0.y);
      ua.u[2] = f2bf(p0.z); ua.u[3] = f2bf(p0.w);
      ua.u[4] = f2bf(p1.x); ua.u[5] = f2bf(p1.y);
      ua.u[6] = f2bf(p1.z); ua.u[7] = f2bf(p1.w);
      int kb = (km << 2) + quad;
      #pragma unroll
      for (int j = 0; j < 8; ++j){
        short8 b = *(const short8*)(&lds[16384 + (j * 16 + c) * 128 + ((kb ^ (c & 7)) << 3)]);
        acc[j] = __builtin_amdgcn_mfma_f32_16x16x32_bf16(ua.v, b, acc[j], 0, 0, 0);
      }
    }
    #pragma unroll
    for (int j = 0; j < 8; ++j){
      int colIdx = j * 16 + c;
      float bvv = bias[colIdx];
      #pragma unroll
      for (int r = 0; r < 4; ++r){
        int row = row0 + quad * 4 + r;
        outf[(size_t)row * DIM + colIdx] = fmaxf(acc[j][r] + bvv, 0.f);
      }
    }
  }
}

// ---- host ------------------------------------------------------------------

extern "C" void kernel_launch(void* const* d_in, const int* in_sizes, int n_in,
                              void* d_out, int out_size, void* d_ws, size_t ws_size,
                              hipStream_t stream)
{
  const float* x   = (const float*)d_in[0];
  const int*   ei  = (const int*)d_in[1];
  const float* Wl1 = (const float*)d_in[2];
  const float* bl1 = (const float*)d_in[3];
  const float* Wr1 = (const float*)d_in[4];
  const float* Wl2 = (const float*)d_in[5];
  const float* bl2 = (const float*)d_in[6];
  const float* Wr2 = (const float*)d_in[7];

  const int N = in_sizes[0] / DIM;
  const int E = in_sizes[1] / 2;
  const int* src  = ei;
  const int* dstI = ei + E;
  const int NB = (N + 511) >> 9;   // 196 (must be <= 255 for k_bin's uchar)

  char* p = (char*)d_ws;
  auto alloc = [&](size_t bytes) -> char* {
    char* r = p; p += (bytes + 255) & ~((size_t)255); return r;
  };
  int* rowptr   = (int*)alloc((size_t)(N + 1) * 4);
  int* deg      = (int*)alloc((size_t)N * 4);   // fallback only
  int* bsum     = (int*)alloc(1024);            // fallback only
  int* bktCnt   = (int*)alloc(1024);
  int* bktBase  = (int*)alloc(2048);            // 257 entries used
  int* bktCur   = (int*)alloc(1024);
  int* col      = (int*)alloc((size_t)E * 4);
  unsigned short* aggb = (unsigned short*)alloc((size_t)N * DIM * 2);
  unsigned short* xb   = (unsigned short*)alloc((size_t)N * DIM * 2);
  unsigned short* h1b  = (unsigned short*)alloc((size_t)N * DIM * 2);
  size_t need_big = (size_t)(p - (char*)d_ws);
  const bool big = (ws_size >= need_big) && (NB <= 255);
  int2* binned = (int2*)aggb;   // overlays aggb (dead until first k_agg write)

  int gE = (E + 255) / 256;
  int gAgg = (N * 64 + 255) / 256;

  if (big){
    hipMemsetAsync(bktCnt, 0, 1024, stream);
    hipMemsetAsync(bktCur, 0, 1024, stream);
    k_hist256<<<1024, 256, 0, stream>>>(dstI, E, bktCnt);
    k_scanB<<<1, 256, 0, stream>>>(bktCnt, bktBase, NB);
    k_bin<<<(E + 4095) / 4096, 256, 0, stream>>>(src, dstI, E, bktBase, bktCur,
                                                 binned, NB);
    k_csr2<<<NB, 256, 0, stream>>>(binned, bktBase, N, rowptr, col);
    int n4 = N * DIM / 4;
    k_cast<<<8192, 256, 0, stream>>>(x, xb, n4);
    k_agg_bf<<<gAgg, 256, 0, stream>>>(xb, rowptr, col, aggb, N);
    k_gemm_r<true><<<512, 256, 0, stream>>>(aggb, xb, Wl1, Wr1, bl1,
                                            nullptr, h1b, N);
    k_agg_bf<<<gAgg, 256, 0, stream>>>(h1b, rowptr, col, aggb, N);
    k_gemm_r<false><<<512, 256, 0, stream>>>(aggb, h1b, Wl2, Wr2, bl2,
                                             (float*)d_out, nullptr, N);
  } else {
    hipMemsetAsync(deg, 0, (size_t)N * 4, stream);
    k_hist<<<gE, 256, 0, stream>>>(dstI, E, deg);
    int nb = (N + 1023) / 1024;
    k_scan1<<<nb, 256, 0, stream>>>(deg, N, rowptr, bsum);
    k_scan2<<<1, 128, 0, stream>>>(bsum, nb);
    k_scan3<<<(N + 255) / 256, 256, 0, stream>>>(rowptr, bsum, N, E, /*cursor=*/deg);
    k_fill<<<gE, 256, 0, stream>>>(src, dstI, E, /*cursor=*/deg, col);
    float* h1 = (float*)d_out;
    k_agg_f32<<<gAgg, 256, 0, stream>>>(x, rowptr, col, aggb, N);
    k_gemm_f<<<512, 256, 0, stream>>>(aggb, x, Wl1, Wr1, bl1, h1, N);
    k_agg_f32<<<gAgg, 256, 0, stream>>>(h1, rowptr, col, aggb, N);
    k_gemm_f<<<512, 256, 0, stream>>>(aggb, h1, Wl2, Wr2, bl2, (float*)d_out, N);
  }
}